// Round 9
// baseline (404.655 us; speedup 1.0000x reference)
//
#include <hip/hip_runtime.h>
#include <hip/hip_fp16.h>

#define DEVFN __device__ __forceinline__

constexpr int N    = 100000;
constexpr int F_IN = 166;
constexpr int HID  = 128;
constexpr int E    = 1600000;

using half8 = __attribute__((ext_vector_type(8))) _Float16;
using f32x4 = __attribute__((ext_vector_type(4))) float;

// ---- workspace layout (bytes, all 16B-aligned; ends 62.1 MB as before) ----
constexpr size_t HW_OFF   = 0;            // hW [N,128] fp16      25.6 MB
constexpr size_t GOUT_OFF = 25600000;     // GAT out [N,128] fp16 25.6 MB; ALIASED by
                                          //   interm [49*40960] i32 8.03 MB during CSR build
constexpr size_t ASRC_OFF = 51200000;     // a_src [N,4] f32       1.6 MB
constexpr size_t ADST_OFF = 52800000;     // a_dst [N,4] f32       1.6 MB
constexpr size_t ROW_OFF  = 54800000;     // rowstart [N+1] i32 (ends 55,200,004)
constexpr size_t BCNT_OFF = 55200016;     // bucket counters [49] i32 (zeroed in k_prep)
constexpr size_t BBASE_OFF= 55600016;     // bucket bases [49] i32
constexpr size_t WPK1_OFF = 55600544;     // Win  packed fp16 frags 49,152 B
constexpr size_t WPK2_OFF = 55649696;     // Wgat packed fp16 frags 32,768 B
constexpr size_t WPK3_OFF = 55682464;     // W1   packed fp16 frags 16,384 B
constexpr size_t CSR_OFF  = 55700000;     // csr_src [E] i32       6.4 MB

// R19 k_proj geometry: 128 rows/block, 4 waves x 32 rows (2 A-frags/wave) —
// each B-fragment global load now feeds 2 MFMAs (R18: k_proj MfmaUtil 2.6%,
// B-load latency-bound with 1 MFMA per B-load).
constexpr int PROJ_ROWS  = 128;
constexpr int PROJ_NB    = (N + PROJ_ROWS - 1) / PROJ_ROWS;    // 782
constexpr int MLP_NB     = (N + 63) / 64;                      // 1563

// CSR-build: 49 coarse buckets of 2048 dst-nodes (dst>>11), fixed capacity
// (uniform E: mu=32768, sigma~180 -> 44-sigma headroom; guarded). R19: the
// whole deg/scan/scatter tail collapsed into k_scanB (49-wide shfl scan) +
// k_binB (one wg per bucket: LDS count -> in-LDS prefix -> dense rowstart ->
// LDS-cursor scatter). Kills the 8x-redundant bucket streams of R18's
// binB1/binB2 and the two scan dispatches.
constexpr int NBUCK     = 49;
constexpr int BCAP      = 40960;
constexpr int BIN_CHUNK = 4096;
constexpr int BIN_NB    = (E + BIN_CHUNK - 1) / BIN_CHUNK;     // 391

DEVFN float lrelu(float e) { return e > 0.0f ? e : 0.2f * e; }

// 16 half-precision messages (2x float4 raw) fma'd into 4x float4 f32 accs.
DEVFN void acc16h(const float4& q0, const float4& q1, const float x,
                  float4& a0, float4& a1, float4& a2, float4& a3)
{
    const __half2* h = (const __half2*)&q0;
    a0.x = fmaf(__low2float(h[0]),  x, a0.x);
    a0.y = fmaf(__high2float(h[0]), x, a0.y);
    a0.z = fmaf(__low2float(h[1]),  x, a0.z);
    a0.w = fmaf(__high2float(h[1]), x, a0.w);
    a1.x = fmaf(__low2float(h[2]),  x, a1.x);
    a1.y = fmaf(__high2float(h[2]), x, a1.y);
    a1.z = fmaf(__low2float(h[3]),  x, a1.z);
    a1.w = fmaf(__high2float(h[3]), x, a1.w);
    const __half2* g = (const __half2*)&q1;
    a2.x = fmaf(__low2float(g[0]),  x, a2.x);
    a2.y = fmaf(__high2float(g[0]), x, a2.y);
    a2.z = fmaf(__low2float(g[1]),  x, a2.z);
    a2.w = fmaf(__high2float(g[1]), x, a2.w);
    a3.x = fmaf(__low2float(g[2]),  x, a3.x);
    a3.y = fmaf(__high2float(g[2]), x, a3.y);
    a3.z = fmaf(__low2float(g[3]),  x, a3.z);
    a3.w = fmaf(__high2float(g[3]), x, a3.w);
}

// ---------------------------------------------------------------------------
// k_prep: pack Win/Wgat/W1 into fp16 MFMA B-fragment layout + zero bcnt.
// ---------------------------------------------------------------------------
__global__ __launch_bounds__(256) void k_prep(const float* __restrict__ Win,
                                              const float* __restrict__ Wgat,
                                              const float* __restrict__ W1,
                                              __half* __restrict__ Wpk1,
                                              __half* __restrict__ Wpk2,
                                              __half* __restrict__ Wpk3,
                                              int* __restrict__ bcnt)
{
    const int idx = blockIdx.x * 256 + threadIdx.x;
    if (idx < NBUCK) bcnt[idx] = 0;
    if (idx < 24576) {                                  // GEMM1: 6 ks * 8 t
        const int i  = idx & 7;
        const int l  = (idx >> 3) & 63;
        const int tt = (idx >> 9) & 7;
        const int ks = idx >> 12;
        const int k   = ks * 32 + (l >> 4) * 8 + i;
        const int col = tt * 16 + (l & 15);
        const float v = (k < F_IN) ? Win[k * HID + col] : 0.0f;
        Wpk1[idx] = __float2half(v);
    } else if (idx < 40960) {                           // GEMM2: 4 ks * 8 t
        const int j  = idx - 24576;
        const int i  = j & 7;
        const int l  = (j >> 3) & 63;
        const int tt = (j >> 9) & 7;
        const int ks = j >> 12;
        const int k   = ks * 32 + (l >> 4) * 8 + i;
        const int col = tt * 16 + (l & 15);
        Wpk2[j] = __float2half(Wgat[k * HID + col]);
    } else {                                            // MLP W1: 4 ks * 4 t
        const int j  = idx - 40960;
        const int i  = j & 7;
        const int l  = (j >> 3) & 63;
        const int tt = (j >> 9) & 3;
        const int ks = j >> 11;
        const int k   = ks * 32 + (l >> 4) * 8 + i;
        const int col = tt * 16 + (l & 15);
        Wpk3[j] = __float2half(W1[k * 64 + col]);
    }
}

// ---------------------------------------------------------------------------
// k_proj R19: 128 rows/block, 4 waves x 32 rows (acc[2][8]). Same verified
// fragment conventions (C/D col=lane&15, row=(lane>>4)*4+reg; m89/m91).
// ---------------------------------------------------------------------------
__global__ __launch_bounds__(256) void k_proj(
    const float* __restrict__ x,
    const __half* __restrict__ Wpk1, const __half* __restrict__ Wpk2,
    const float* __restrict__ bin,
    const float* __restrict__ attS, const float* __restrict__ attD,
    __half* __restrict__ hWh, float* __restrict__ aS, float* __restrict__ aD)
{
    __shared__ __align__(16) __half sh[PROJ_ROWS * 200];   // 51200 B

    const int t    = threadIdx.x;
    const int row0 = blockIdx.x * PROJ_ROWS;
    const int w    = t >> 6;
    const int lane = t & 63;
    const int l15  = lane & 15;
    const int g    = lane >> 4;
    const int ar0  = w * 32 + l15;      // A-frag rows (two 16-row subtiles)
    const int ar1  = ar0 + 16;

    for (int idx = t; idx < PROJ_ROWS * 100; idx += 256) {
        const int r   = idx / 100;
        const int kk2 = (idx - r * 100) * 2;
        float2 v = make_float2(0.f, 0.f);
        const int row = row0 + r;
        if (row < N && kk2 < F_IN)
            v = *(const float2*)&x[(size_t)row * F_IN + kk2];
        *(__half2*)&sh[r * 200 + kk2] = __float22half2_rn(v);
    }
    __syncthreads();

    f32x4 acc0[8], acc1[8];
#pragma unroll
    for (int tt = 0; tt < 8; ++tt)
#pragma unroll
        for (int q = 0; q < 4; ++q) { acc0[tt][q] = 0.0f; acc1[tt][q] = 0.0f; }

    // ---- GEMM1: h = relu(x @ Win + bin); K padded to 192, 6 K-steps ----
#pragma unroll
    for (int ks = 0; ks < 6; ++ks) {
        const half8 a0 = *(const half8*)&sh[ar0 * 200 + ks * 32 + g * 8];
        const half8 a1 = *(const half8*)&sh[ar1 * 200 + ks * 32 + g * 8];
        const half8* bp = (const half8*)&Wpk1[ks * 4096 + lane * 8];
#pragma unroll
        for (int tt = 0; tt < 8; ++tt) {
            const half8 b = bp[tt * 64];
            acc0[tt] = __builtin_amdgcn_mfma_f32_16x16x32_f16(a0, b, acc0[tt], 0, 0, 0);
            acc1[tt] = __builtin_amdgcn_mfma_f32_16x16x32_f16(a1, b, acc1[tt], 0, 0, 0);
        }
    }

    __syncthreads();

    // ---- epilogue 1: h = relu(acc + bin) -> fp16 LDS, stride 136 ----
#pragma unroll
    for (int tt = 0; tt < 8; ++tt) {
        const int col = tt * 16 + l15;
        const float bv = bin[col];
#pragma unroll
        for (int rg = 0; rg < 4; ++rg) {
            const int r = w * 32 + g * 4 + rg;
            sh[r * 136 + col]        = __float2half(fmaxf(acc0[tt][rg] + bv, 0.0f));
            sh[(r + 16) * 136 + col] = __float2half(fmaxf(acc1[tt][rg] + bv, 0.0f));
        }
    }
    __syncthreads();

#pragma unroll
    for (int tt = 0; tt < 8; ++tt)
#pragma unroll
        for (int q = 0; q < 4; ++q) { acc0[tt][q] = 0.0f; acc1[tt][q] = 0.0f; }

    // ---- GEMM2: hW = h @ Wgat; K = 128, 4 K-steps ----
#pragma unroll
    for (int ks = 0; ks < 4; ++ks) {
        const half8 a0 = *(const half8*)&sh[ar0 * 136 + ks * 32 + g * 8];
        const half8 a1 = *(const half8*)&sh[ar1 * 136 + ks * 32 + g * 8];
        const half8* bp = (const half8*)&Wpk2[ks * 4096 + lane * 8];
#pragma unroll
        for (int tt = 0; tt < 8; ++tt) {
            const half8 b = bp[tt * 64];
            acc0[tt] = __builtin_amdgcn_mfma_f32_16x16x32_f16(a0, b, acc0[tt], 0, 0, 0);
            acc1[tt] = __builtin_amdgcn_mfma_f32_16x16x32_f16(a1, b, acc1[tt], 0, 0, 0);
        }
    }

    // ---- epilogue 2a: aS/aD from C-frags, both 16-row halves ----
    float asv[8], adv[8];
#pragma unroll
    for (int tt = 0; tt < 8; ++tt) {
        asv[tt] = attS[tt * 16 + l15];
        adv[tt] = attD[tt * 16 + l15];
    }
#pragma unroll
    for (int half = 0; half < 2; ++half) {
        const f32x4* ac = half ? acc1 : acc0;
        const int grow0 = row0 + w * 32 + half * 16 + g * 4;
        float psb[4][4], pdb[4][4];
#pragma unroll
        for (int rg = 0; rg < 4; ++rg) {
#pragma unroll
            for (int h = 0; h < 4; ++h) {
                float ps = ac[2*h][rg] * asv[2*h] + ac[2*h+1][rg] * asv[2*h+1];
                float pd = ac[2*h][rg] * adv[2*h] + ac[2*h+1][rg] * adv[2*h+1];
#pragma unroll
                for (int off = 1; off <= 8; off <<= 1) {
                    ps += __shfl_xor(ps, off);
                    pd += __shfl_xor(pd, off);
                }
                psb[rg][h] = ps; pdb[rg][h] = pd;
            }
        }
        if (l15 == 0) {
#pragma unroll
            for (int rg = 0; rg < 4; ++rg) {
                const int row = grow0 + rg;
                if (row < N) {
                    *(float4*)&aS[row * 4] = make_float4(psb[rg][0], psb[rg][1], psb[rg][2], psb[rg][3]);
                    *(float4*)&aD[row * 4] = make_float4(pdb[rg][0], pdb[rg][1], pdb[rg][2], pdb[rg][3]);
                }
            }
        }
    }

    // ---- epilogue 2b: hW -> LDS re-stage -> coalesced dwordx4 stores ----
    __syncthreads();
#pragma unroll
    for (int tt = 0; tt < 8; ++tt) {
        const int col = tt * 16 + l15;
#pragma unroll
        for (int rg = 0; rg < 4; ++rg) {
            const int r = w * 32 + g * 4 + rg;
            sh[r * 136 + col]        = __float2half(acc0[tt][rg]);
            sh[(r + 16) * 136 + col] = __float2half(acc1[tt][rg]);
        }
    }
    __syncthreads();
    for (int idx = t; idx < PROJ_ROWS * 16; idx += 256) {
        const int r  = idx >> 4;
        const int c8 = idx & 15;
        const int row = row0 + r;
        if (row < N) {
            const uint4 v = *(const uint4*)&sh[r * 136 + c8 * 8];
            *(uint4*)&hWh[(size_t)row * HID + c8 * 8] = v;
        }
    }
}

// ---------------------------------------------------------------------------
// Pass A: bin edges into 49 fixed-capacity dst-buckets (unchanged from R18).
// ---------------------------------------------------------------------------
__global__ __launch_bounds__(256) void k_binA(const int* __restrict__ ei,
                                              int* __restrict__ bcnt,
                                              int* __restrict__ interm)
{
    __shared__ int hist[NBUCK], base[NBUCK], off[NBUCK];
    const int t  = threadIdx.x;
    const int i0 = blockIdx.x * BIN_CHUNK;

    int pk[16], bk[16];
    if (t < NBUCK) hist[t] = 0;
    __syncthreads();
#pragma unroll
    for (int j = 0; j < 16; ++j) {
        const int i = i0 + j * 256 + t;
        bk[j] = -1;
        if (i < E) {
            const int s = ei[i], d = ei[E + i];
            const int b = d >> 11;
            bk[j] = b;
            pk[j] = s | ((d & 2047) << 17);
            atomicAdd(&hist[b], 1);
        }
    }
    __syncthreads();
    if (t < NBUCK) { base[t] = atomicAdd(&bcnt[t], hist[t]); off[t] = 0; }
    __syncthreads();
#pragma unroll
    for (int j = 0; j < 16; ++j) {
        if (bk[j] >= 0) {
            const int p   = atomicAdd(&off[bk[j]], 1);
            const int pos = base[bk[j]] + p;
            if (pos < BCAP) interm[bk[j] * BCAP + pos] = pk[j];
        }
    }
}

// ---------------------------------------------------------------------------
// k_scanB: exclusive prefix over the 49 bucket counts (one wave64 shfl scan).
// ---------------------------------------------------------------------------
__global__ __launch_bounds__(64) void k_scanB(const int* __restrict__ bcnt,
                                              int* __restrict__ bbase,
                                              int* __restrict__ rowstart)
{
    const int t = threadIdx.x;
    const int v = (t < NBUCK) ? min(bcnt[t], BCAP) : 0;
    int inc = v;
#pragma unroll
    for (int off = 1; off < 64; off <<= 1) {
        const int n = __shfl_up(inc, off);
        if (t >= off) inc += n;
    }
    if (t < NBUCK) bbase[t] = inc - v;
    if (t == 0) rowstart[N] = E;
}

// ---------------------------------------------------------------------------
// k_binB R19: one wg per bucket. LDS degree count (2048 cursors) -> in-LDS
// prefix -> dense rowstart write -> LDS-cursor scatter to an exclusive csr
// window. Bucket streamed exactly twice; replaces binB1+binB2+scan1+scan23.
// ---------------------------------------------------------------------------
__global__ __launch_bounds__(256) void k_binB(const int* __restrict__ interm,
                                              const int* __restrict__ bcnt,
                                              const int* __restrict__ bbase,
                                              int* __restrict__ rowstart,
                                              int* __restrict__ csr)
{
    __shared__ int cnt[2048];
    __shared__ int wsum[256];
    const int t      = threadIdx.x;
    const int bucket = blockIdx.x;

    for (int i = t; i < 2048; i += 256) cnt[i] = 0;
    __syncthreads();

    const int total = min(bcnt[bucket], BCAP);
    const int beg   = bucket * BCAP;
    for (int i = beg + t; i < beg + total; i += 256)
        atomicAdd(&cnt[interm[i] >> 17], 1);
    __syncthreads();

    int loc[8];
    int s = 0;
#pragma unroll
    for (int j = 0; j < 8; ++j) { loc[j] = cnt[t * 8 + j]; s += loc[j]; }
    wsum[t] = s;
    __syncthreads();
    for (int off = 1; off < 256; off <<= 1) {
        const int v = (t >= off) ? wsum[t - off] : 0;
        __syncthreads();
        wsum[t] += v;
        __syncthreads();
    }
    int run = bbase[bucket] + wsum[t] - s;
#pragma unroll
    for (int j = 0; j < 8; ++j) {
        cnt[t * 8 + j] = run;
        const int node = bucket * 2048 + t * 8 + j;
        if (node < N) rowstart[node] = run;
        run += loc[j];
    }
    __syncthreads();

    for (int i = beg + t; i < beg + total; i += 256) {
        const int p   = interm[i];
        const int pos = atomicAdd(&cnt[p >> 17], 1);
        csr[pos] = p & 0x1FFFF;
    }
}

// ---------------------------------------------------------------------------
// K_agg (R16/R18, unchanged): one wave per dst node; fp16 hW gather, f32
// accum; normalize + b_gat -> fp16 gout. R18 counters: 78 us, HBM 43%,
// VALU 55% — dual-bound; untouched this round.
// ---------------------------------------------------------------------------
__global__ __launch_bounds__(256) void k_agg(
    const int* __restrict__ rowstart, const int* __restrict__ csr,
    const float* __restrict__ aS, const float* __restrict__ aD,
    const __half* __restrict__ hWh, const float4* __restrict__ bgat4,
    __half* __restrict__ gout)
{
    const int t = threadIdx.x;
    const int w = t >> 6;
    const int n = blockIdx.x * 4 + w;
    const int lane = t & 63;
    const int slot = lane >> 3;      // 8 parallel edge slots
    const int cg   = lane & 7;       // colgroup: cols [cg*16, cg*16+16)
    const int head = cg >> 1;

    const int r0 = rowstart[n], r1 = rowstart[n + 1];
    const float adh = aD[n * 4 + head];

    float4 a0 = {0.f,0.f,0.f,0.f}, a1 = {0.f,0.f,0.f,0.f};
    float4 a2 = {0.f,0.f,0.f,0.f}, a3 = {0.f,0.f,0.f,0.f};
    float ss = 0.0f;

    if (slot == 0) {
        const float x0 = __expf(lrelu(aS[n * 4 + head] + adh));
        const float4* p0 = (const float4*)&hWh[(size_t)n * HID + cg * 16];
        const float4 q0 = p0[0], q1 = p0[1];
        acc16h(q0, q1, x0, a0, a1, a2, a3);
        ss += x0;
    }

    int j = r0 + slot;
    for (; j + 8 < r1; j += 16) {
        const int s0 = csr[j], s1 = csr[j + 8];
        const float x0 = __expf(lrelu(aS[s0 * 4 + head] + adh));
        const float x1 = __expf(lrelu(aS[s1 * 4 + head] + adh));
        const float4* p0 = (const float4*)&hWh[(size_t)s0 * HID + cg * 16];
        const float4* p1 = (const float4*)&hWh[(size_t)s1 * HID + cg * 16];
        const float4 q00 = p0[0], q01 = p0[1];
        const float4 q10 = p1[0], q11 = p1[1];
        acc16h(q00, q01, x0, a0, a1, a2, a3);
        acc16h(q10, q11, x1, a0, a1, a2, a3);
        ss += x0 + x1;
    }
    if (j < r1) {
        const int s0 = csr[j];
        const float x0 = __expf(lrelu(aS[s0 * 4 + head] + adh));
        const float4* p0 = (const float4*)&hWh[(size_t)s0 * HID + cg * 16];
        const float4 q0 = p0[0], q1 = p0[1];
        acc16h(q0, q1, x0, a0, a1, a2, a3);
        ss += x0;
    }

#pragma unroll
    for (int off = 8; off <= 32; off <<= 1) {
        a0.x += __shfl_xor(a0.x, off); a0.y += __shfl_xor(a0.y, off);
        a0.z += __shfl_xor(a0.z, off); a0.w += __shfl_xor(a0.w, off);
        a1.x += __shfl_xor(a1.x, off); a1.y += __shfl_xor(a1.y, off);
        a1.z += __shfl_xor(a1.z, off); a1.w += __shfl_xor(a1.w, off);
        a2.x += __shfl_xor(a2.x, off); a2.y += __shfl_xor(a2.y, off);
        a2.z += __shfl_xor(a2.z, off); a2.w += __shfl_xor(a2.w, off);
        a3.x += __shfl_xor(a3.x, off); a3.y += __shfl_xor(a3.y, off);
        a3.z += __shfl_xor(a3.z, off); a3.w += __shfl_xor(a3.w, off);
        ss += __shfl_xor(ss, off);
    }

    if (slot == 0) {
        const float inv = 1.0f / (ss + 1e-16f);
        const float4 bg0 = bgat4[cg * 4 + 0];
        const float4 bg1 = bgat4[cg * 4 + 1];
        const float4 bg2 = bgat4[cg * 4 + 2];
        const float4 bg3 = bgat4[cg * 4 + 3];
        const __half2 h0 = __float22half2_rn(make_float2(a0.x*inv+bg0.x, a0.y*inv+bg0.y));
        const __half2 h1 = __float22half2_rn(make_float2(a0.z*inv+bg0.z, a0.w*inv+bg0.w));
        const __half2 h2 = __float22half2_rn(make_float2(a1.x*inv+bg1.x, a1.y*inv+bg1.y));
        const __half2 h3 = __float22half2_rn(make_float2(a1.z*inv+bg1.z, a1.w*inv+bg1.w));
        const __half2 h4 = __float22half2_rn(make_float2(a2.x*inv+bg2.x, a2.y*inv+bg2.y));
        const __half2 h5 = __float22half2_rn(make_float2(a2.z*inv+bg2.z, a2.w*inv+bg2.w));
        const __half2 h6 = __float22half2_rn(make_float2(a3.x*inv+bg3.x, a3.y*inv+bg3.y));
        const __half2 h7 = __float22half2_rn(make_float2(a3.z*inv+bg3.z, a3.w*inv+bg3.w));
        uint4 p0, p1;
        p0.x = *(const unsigned*)&h0; p0.y = *(const unsigned*)&h1;
        p0.z = *(const unsigned*)&h2; p0.w = *(const unsigned*)&h3;
        p1.x = *(const unsigned*)&h4; p1.y = *(const unsigned*)&h5;
        p1.z = *(const unsigned*)&h6; p1.w = *(const unsigned*)&h7;
        __half* gp = &gout[(size_t)n * HID + cg * 16];
        *(uint4*)gp = p0;
        *(uint4*)(gp + 8) = p1;
    }
}

// ---------------------------------------------------------------------------
// k_mlp (R16, unchanged): MFMA MLP head.
// ---------------------------------------------------------------------------
__global__ __launch_bounds__(256) void k_mlp(
    const __half* __restrict__ gout, const __half* __restrict__ Wpk3,
    const float* __restrict__ b1, const float* __restrict__ W2,
    const float* __restrict__ b2, float2* __restrict__ out)
{
    const int t = threadIdx.x;
    const int w = t >> 6, lane = t & 63;
    const int l15 = lane & 15, g = lane >> 4;
    const int rowbase = blockIdx.x * 64 + w * 16;
    const int arow = rowbase + l15;
    const bool arok = (arow < N);

    f32x4 acc[4];
#pragma unroll
    for (int tt = 0; tt < 4; ++tt)
#pragma unroll
        for (int q = 0; q < 4; ++q) acc[tt][q] = 0.0f;

#pragma unroll
    for (int ks = 0; ks < 4; ++ks) {
        half8 a;
#pragma unroll
        for (int i = 0; i < 8; ++i) a[i] = (_Float16)0;
        if (arok) a = *(const half8*)&gout[(size_t)arow * HID + ks * 32 + g * 8];
        const half8* bp = (const half8*)&Wpk3[ks * 2048 + lane * 8];
#pragma unroll
        for (int tt = 0; tt < 4; ++tt)
            acc[tt] = __builtin_amdgcn_mfma_f32_16x16x32_f16(a, bp[tt * 64], acc[tt], 0, 0, 0);
    }

    float l0[4] = {0.f, 0.f, 0.f, 0.f}, l1[4] = {0.f, 0.f, 0.f, 0.f};
#pragma unroll
    for (int tt = 0; tt < 4; ++tt) {
        const int col = tt * 16 + l15;
        const float bv = b1[col];
        const float2 wv = *(const float2*)&W2[col * 2];
#pragma unroll
        for (int rg = 0; rg < 4; ++rg) {
            const float h2 = fmaxf(acc[tt][rg] + bv, 0.0f);
            l0[rg] = fmaf(h2, wv.x, l0[rg]);
            l1[rg] = fmaf(h2, wv.y, l1[rg]);
        }
    }
#pragma unroll
    for (int off = 1; off <= 8; off <<= 1) {
#pragma unroll
        for (int rg = 0; rg < 4; ++rg) {
            l0[rg] += __shfl_xor(l0[rg], off);
            l1[rg] += __shfl_xor(l1[rg], off);
        }
    }
    if (l15 == 0) {
        const float b20 = b2[0], b21 = b2[1];
#pragma unroll
        for (int rg = 0; rg < 4; ++rg) {
            const int row = rowbase + g * 4 + rg;
            if (row < N) out[row] = make_float2(l0[rg] + b20, l1[rg] + b21);
        }
    }
}

extern "C" void kernel_launch(void* const* d_in, const int* in_sizes, int n_in,
                              void* d_out, int out_size, void* d_ws, size_t ws_size,
                              hipStream_t stream) {
    const float* x     = (const float*)d_in[0];
    const int*   ei    = (const int*)d_in[1];
    const float* Win   = (const float*)d_in[2];
    const float* bin   = (const float*)d_in[3];
    const float* Wgat  = (const float*)d_in[4];
    const float* attS  = (const float*)d_in[5];
    const float* attD  = (const float*)d_in[6];
    const float* bgat  = (const float*)d_in[7];
    const float* W1    = (const float*)d_in[8];
    const float* b1    = (const float*)d_in[9];
    const float* W2    = (const float*)d_in[10];
    const float* b2    = (const float*)d_in[11];

    char* ws = (char*)d_ws;
    __half* hWh   = (__half*)(ws + HW_OFF);
    __half* gout  = (__half*)(ws + GOUT_OFF);
    int*   interm = (int*)(ws + GOUT_OFF);    // aliases gout; dead before k_agg
    float* aS     = (float*)(ws + ASRC_OFF);
    float* aD     = (float*)(ws + ADST_OFF);
    int*   row    = (int*)(ws + ROW_OFF);
    int*   bcnt   = (int*)(ws + BCNT_OFF);
    int*   bbase  = (int*)(ws + BBASE_OFF);
    __half* Wpk1  = (__half*)(ws + WPK1_OFF);
    __half* Wpk2  = (__half*)(ws + WPK2_OFF);
    __half* Wpk3  = (__half*)(ws + WPK3_OFF);
    int*   csr    = (int*)(ws + CSR_OFF);

    k_prep<<<192, 256, 0, stream>>>(Win, Wgat, W1, Wpk1, Wpk2, Wpk3, bcnt);
    k_proj<<<PROJ_NB, 256, 0, stream>>>(x, Wpk1, Wpk2, bin, attS, attD,
                                        hWh, aS, aD);
    k_binA<<<BIN_NB, 256, 0, stream>>>(ei, bcnt, interm);
    k_scanB<<<1, 64, 0, stream>>>(bcnt, bbase, row);
    k_binB<<<NBUCK, 256, 0, stream>>>(interm, bcnt, bbase, row, csr);
    k_agg<<<N / 4, 256, 0, stream>>>(row, csr, aS, aD, hWh,
                                     (const float4*)bgat, gout);
    k_mlp<<<MLP_NB, 256, 0, stream>>>(gout, Wpk3, b1, W2, b2, (float2*)d_out);
}

// Round 10
// 352.000 us; speedup vs baseline: 1.1496x; 1.1496x over previous
//
#include <hip/hip_runtime.h>
#include <hip/hip_fp16.h>

#define DEVFN __device__ __forceinline__

constexpr int N    = 100000;
constexpr int F_IN = 166;
constexpr int HID  = 128;
constexpr int E    = 1600000;

using half8 = __attribute__((ext_vector_type(8))) _Float16;
using f32x4 = __attribute__((ext_vector_type(4))) float;

// ---- workspace layout (bytes, all 16B-aligned; ends 62.1 MB as before) ----
constexpr size_t HW_OFF   = 0;            // hW [N,128] fp16      25.6 MB
constexpr size_t GOUT_OFF = 25600000;     // GAT out [N,128] fp16 25.6 MB; ALIASED by
                                          //   interm [49*40960] i32 8.03 MB during CSR build
constexpr size_t ASRC_OFF = 51200000;     // a_src [N,4] f32       1.6 MB
constexpr size_t ADST_OFF = 52800000;     // a_dst [N,4] f32       1.6 MB
constexpr size_t ROW_OFF  = 54800000;     // rowstart [N+1] i32 (ends 55,200,004)
constexpr size_t BCNT_OFF = 55200016;     // bucket counters [49] i32 (zeroed in k_prep)
constexpr size_t BBASE_OFF= 55600016;     // bucket bases [49] i32
constexpr size_t WPK1_OFF = 55600544;     // Win  packed fp16 frags 49,152 B
constexpr size_t WPK2_OFF = 55649696;     // Wgat packed fp16 frags 32,768 B
constexpr size_t WPK3_OFF = 55682464;     // W1   packed fp16 frags 16,384 B
constexpr size_t CSR_OFF  = 55700000;     // csr_src [E] i32       6.4 MB

// R20: k_proj reverted to the R18 geometry — 64 rows/block, LDS 25.6 KB,
// VGPR ~72, occupancy 26%, ~75us. R19 lesson: 128-row retile (2x B-reuse)
// halved occupancy (9%) and REGRESSED 1.6x — k_proj is latency-bound, more
// resident waves beat less B-traffic. Do not revisit bigger tiles here.
constexpr int PROJ_ROWS  = 64;
constexpr int PROJ_NB    = (N + PROJ_ROWS - 1) / PROJ_ROWS;    // 1563
constexpr int MLP_NB     = (N + 63) / 64;                      // 1563

// CSR-build (R19, kept — saved ~20us vs R18 chain): 49 coarse buckets of
// 2048 dst-nodes, fixed capacity (uniform E: mu=32768, sigma~180 -> 44-sigma
// headroom; guarded). binA -> scanB (49-wide shfl scan) -> binB (one wg per
// bucket: LDS count -> in-LDS prefix -> dense rowstart -> LDS-cursor scatter).
constexpr int NBUCK     = 49;
constexpr int BCAP      = 40960;
constexpr int BIN_CHUNK = 4096;
constexpr int BIN_NB    = (E + BIN_CHUNK - 1) / BIN_CHUNK;     // 391

DEVFN float lrelu(float e) { return e > 0.0f ? e : 0.2f * e; }

// 16 half-precision messages (2x float4 raw) fma'd into 4x float4 f32 accs.
DEVFN void acc16h(const float4& q0, const float4& q1, const float x,
                  float4& a0, float4& a1, float4& a2, float4& a3)
{
    const __half2* h = (const __half2*)&q0;
    a0.x = fmaf(__low2float(h[0]),  x, a0.x);
    a0.y = fmaf(__high2float(h[0]), x, a0.y);
    a0.z = fmaf(__low2float(h[1]),  x, a0.z);
    a0.w = fmaf(__high2float(h[1]), x, a0.w);
    a1.x = fmaf(__low2float(h[2]),  x, a1.x);
    a1.y = fmaf(__high2float(h[2]), x, a1.y);
    a1.z = fmaf(__low2float(h[3]),  x, a1.z);
    a1.w = fmaf(__high2float(h[3]), x, a1.w);
    const __half2* g = (const __half2*)&q1;
    a2.x = fmaf(__low2float(g[0]),  x, a2.x);
    a2.y = fmaf(__high2float(g[0]), x, a2.y);
    a2.z = fmaf(__low2float(g[1]),  x, a2.z);
    a2.w = fmaf(__high2float(g[1]), x, a2.w);
    a3.x = fmaf(__low2float(g[2]),  x, a3.x);
    a3.y = fmaf(__high2float(g[2]), x, a3.y);
    a3.z = fmaf(__low2float(g[3]),  x, a3.z);
    a3.w = fmaf(__high2float(g[3]), x, a3.w);
}

// ---------------------------------------------------------------------------
// k_prep: pack Win/Wgat/W1 into fp16 MFMA B-fragment layout + zero bcnt.
// ---------------------------------------------------------------------------
__global__ __launch_bounds__(256) void k_prep(const float* __restrict__ Win,
                                              const float* __restrict__ Wgat,
                                              const float* __restrict__ W1,
                                              __half* __restrict__ Wpk1,
                                              __half* __restrict__ Wpk2,
                                              __half* __restrict__ Wpk3,
                                              int* __restrict__ bcnt)
{
    const int idx = blockIdx.x * 256 + threadIdx.x;
    if (idx < NBUCK) bcnt[idx] = 0;
    if (idx < 24576) {                                  // GEMM1: 6 ks * 8 t
        const int i  = idx & 7;
        const int l  = (idx >> 3) & 63;
        const int tt = (idx >> 9) & 7;
        const int ks = idx >> 12;
        const int k   = ks * 32 + (l >> 4) * 8 + i;
        const int col = tt * 16 + (l & 15);
        const float v = (k < F_IN) ? Win[k * HID + col] : 0.0f;
        Wpk1[idx] = __float2half(v);
    } else if (idx < 40960) {                           // GEMM2: 4 ks * 8 t
        const int j  = idx - 24576;
        const int i  = j & 7;
        const int l  = (j >> 3) & 63;
        const int tt = (j >> 9) & 7;
        const int ks = j >> 12;
        const int k   = ks * 32 + (l >> 4) * 8 + i;
        const int col = tt * 16 + (l & 15);
        Wpk2[j] = __float2half(Wgat[k * HID + col]);
    } else {                                            // MLP W1: 4 ks * 4 t
        const int j  = idx - 40960;
        const int i  = j & 7;
        const int l  = (j >> 3) & 63;
        const int tt = (j >> 9) & 3;
        const int ks = j >> 11;
        const int k   = ks * 32 + (l >> 4) * 8 + i;
        const int col = tt * 16 + (l & 15);
        Wpk3[j] = __float2half(W1[k * 64 + col]);
    }
}

// ---------------------------------------------------------------------------
// k_proj (R18 geometry, restored): MFMA, 64 rows/block, 4 waves x 16 rows,
// 8 col-tiles. A-frags from padded fp16 LDS; B-frags from k_prep packed
// global (L2-hot). C/D col=lane&15, row=(lane>>4)*4+reg (m89/m91).
// ---------------------------------------------------------------------------
__global__ __launch_bounds__(256) void k_proj(
    const float* __restrict__ x,
    const __half* __restrict__ Wpk1, const __half* __restrict__ Wpk2,
    const float* __restrict__ bin,
    const float* __restrict__ attS, const float* __restrict__ attD,
    __half* __restrict__ hWh, float* __restrict__ aS, float* __restrict__ aD)
{
    __shared__ __align__(16) __half sh[PROJ_ROWS * 200];   // 25600 B

    const int t    = threadIdx.x;
    const int row0 = blockIdx.x * PROJ_ROWS;
    const int w    = t >> 6;
    const int lane = t & 63;
    const int l15  = lane & 15;
    const int g    = lane >> 4;
    const int arow = w * 16 + l15;

    for (int idx = t; idx < PROJ_ROWS * 100; idx += 256) {
        const int r   = idx / 100;
        const int kk2 = (idx - r * 100) * 2;
        float2 v = make_float2(0.f, 0.f);
        const int row = row0 + r;
        if (row < N && kk2 < F_IN)
            v = *(const float2*)&x[(size_t)row * F_IN + kk2];
        *(__half2*)&sh[r * 200 + kk2] = __float22half2_rn(v);
    }
    __syncthreads();

    f32x4 acc[8];
#pragma unroll
    for (int tt = 0; tt < 8; ++tt)
#pragma unroll
        for (int q = 0; q < 4; ++q) acc[tt][q] = 0.0f;

#pragma unroll
    for (int ks = 0; ks < 6; ++ks) {
        const half8 a = *(const half8*)&sh[arow * 200 + ks * 32 + g * 8];
        const half8* bp = (const half8*)&Wpk1[ks * 4096 + lane * 8];
#pragma unroll
        for (int tt = 0; tt < 8; ++tt) {
            acc[tt] = __builtin_amdgcn_mfma_f32_16x16x32_f16(a, bp[tt * 64], acc[tt], 0, 0, 0);
        }
    }

    __syncthreads();

#pragma unroll
    for (int tt = 0; tt < 8; ++tt) {
        const int col = tt * 16 + l15;
        const float bv = bin[col];
#pragma unroll
        for (int rg = 0; rg < 4; ++rg) {
            const int r = w * 16 + g * 4 + rg;
            sh[r * 136 + col] = __float2half(fmaxf(acc[tt][rg] + bv, 0.0f));
        }
    }
    __syncthreads();

#pragma unroll
    for (int tt = 0; tt < 8; ++tt)
#pragma unroll
        for (int q = 0; q < 4; ++q) acc[tt][q] = 0.0f;

#pragma unroll
    for (int ks = 0; ks < 4; ++ks) {
        const half8 a = *(const half8*)&sh[arow * 136 + ks * 32 + g * 8];
        const half8* bp = (const half8*)&Wpk2[ks * 4096 + lane * 8];
#pragma unroll
        for (int tt = 0; tt < 8; ++tt) {
            acc[tt] = __builtin_amdgcn_mfma_f32_16x16x32_f16(a, bp[tt * 64], acc[tt], 0, 0, 0);
        }
    }

    const int grow0 = row0 + w * 16 + g * 4;
    float asv[8], adv[8];
#pragma unroll
    for (int tt = 0; tt < 8; ++tt) {
        asv[tt] = attS[tt * 16 + l15];
        adv[tt] = attD[tt * 16 + l15];
    }
    float psb[4][4], pdb[4][4];
#pragma unroll
    for (int rg = 0; rg < 4; ++rg) {
#pragma unroll
        for (int h = 0; h < 4; ++h) {
            float ps = acc[2*h][rg] * asv[2*h] + acc[2*h+1][rg] * asv[2*h+1];
            float pd = acc[2*h][rg] * adv[2*h] + acc[2*h+1][rg] * adv[2*h+1];
#pragma unroll
            for (int off = 1; off <= 8; off <<= 1) {
                ps += __shfl_xor(ps, off);
                pd += __shfl_xor(pd, off);
            }
            psb[rg][h] = ps; pdb[rg][h] = pd;
        }
    }
    if (l15 == 0) {
#pragma unroll
        for (int rg = 0; rg < 4; ++rg) {
            const int row = grow0 + rg;
            if (row < N) {
                *(float4*)&aS[row * 4] = make_float4(psb[rg][0], psb[rg][1], psb[rg][2], psb[rg][3]);
                *(float4*)&aD[row * 4] = make_float4(pdb[rg][0], pdb[rg][1], pdb[rg][2], pdb[rg][3]);
            }
        }
    }

    __syncthreads();
#pragma unroll
    for (int tt = 0; tt < 8; ++tt) {
        const int col = tt * 16 + l15;
#pragma unroll
        for (int rg = 0; rg < 4; ++rg) {
            const int r = w * 16 + g * 4 + rg;
            sh[r * 136 + col] = __float2half(acc[tt][rg]);
        }
    }
    __syncthreads();
    for (int idx = t; idx < PROJ_ROWS * 16; idx += 256) {
        const int r  = idx >> 4;
        const int c8 = idx & 15;
        const int row = row0 + r;
        if (row < N) {
            const uint4 v = *(const uint4*)&sh[r * 136 + c8 * 8];
            *(uint4*)&hWh[(size_t)row * HID + c8 * 8] = v;
        }
    }
}

// ---------------------------------------------------------------------------
// Pass A: bin edges into 49 fixed-capacity dst-buckets.
// ---------------------------------------------------------------------------
__global__ __launch_bounds__(256) void k_binA(const int* __restrict__ ei,
                                              int* __restrict__ bcnt,
                                              int* __restrict__ interm)
{
    __shared__ int hist[NBUCK], base[NBUCK], off[NBUCK];
    const int t  = threadIdx.x;
    const int i0 = blockIdx.x * BIN_CHUNK;

    int pk[16], bk[16];
    if (t < NBUCK) hist[t] = 0;
    __syncthreads();
#pragma unroll
    for (int j = 0; j < 16; ++j) {
        const int i = i0 + j * 256 + t;
        bk[j] = -1;
        if (i < E) {
            const int s = ei[i], d = ei[E + i];
            const int b = d >> 11;
            bk[j] = b;
            pk[j] = s | ((d & 2047) << 17);
            atomicAdd(&hist[b], 1);
        }
    }
    __syncthreads();
    if (t < NBUCK) { base[t] = atomicAdd(&bcnt[t], hist[t]); off[t] = 0; }
    __syncthreads();
#pragma unroll
    for (int j = 0; j < 16; ++j) {
        if (bk[j] >= 0) {
            const int p   = atomicAdd(&off[bk[j]], 1);
            const int pos = base[bk[j]] + p;
            if (pos < BCAP) interm[bk[j] * BCAP + pos] = pk[j];
        }
    }
}

// ---------------------------------------------------------------------------
// k_scanB: exclusive prefix over the 49 bucket counts (one wave64 shfl scan).
// ---------------------------------------------------------------------------
__global__ __launch_bounds__(64) void k_scanB(const int* __restrict__ bcnt,
                                              int* __restrict__ bbase,
                                              int* __restrict__ rowstart)
{
    const int t = threadIdx.x;
    const int v = (t < NBUCK) ? min(bcnt[t], BCAP) : 0;
    int inc = v;
#pragma unroll
    for (int off = 1; off < 64; off <<= 1) {
        const int n = __shfl_up(inc, off);
        if (t >= off) inc += n;
    }
    if (t < NBUCK) bbase[t] = inc - v;
    if (t == 0) rowstart[N] = E;
}

// ---------------------------------------------------------------------------
// k_binB: one wg per bucket. LDS degree count (2048 cursors) -> in-LDS
// prefix -> dense rowstart write -> LDS-cursor scatter to exclusive csr
// window. Bucket streamed exactly twice.
// ---------------------------------------------------------------------------
__global__ __launch_bounds__(256) void k_binB(const int* __restrict__ interm,
                                              const int* __restrict__ bcnt,
                                              const int* __restrict__ bbase,
                                              int* __restrict__ rowstart,
                                              int* __restrict__ csr)
{
    __shared__ int cnt[2048];
    __shared__ int wsum[256];
    const int t      = threadIdx.x;
    const int bucket = blockIdx.x;

    for (int i = t; i < 2048; i += 256) cnt[i] = 0;
    __syncthreads();

    const int total = min(bcnt[bucket], BCAP);
    const int beg   = bucket * BCAP;
    for (int i = beg + t; i < beg + total; i += 256)
        atomicAdd(&cnt[interm[i] >> 17], 1);
    __syncthreads();

    int loc[8];
    int s = 0;
#pragma unroll
    for (int j = 0; j < 8; ++j) { loc[j] = cnt[t * 8 + j]; s += loc[j]; }
    wsum[t] = s;
    __syncthreads();
    for (int off = 1; off < 256; off <<= 1) {
        const int v = (t >= off) ? wsum[t - off] : 0;
        __syncthreads();
        wsum[t] += v;
        __syncthreads();
    }
    int run = bbase[bucket] + wsum[t] - s;
#pragma unroll
    for (int j = 0; j < 8; ++j) {
        cnt[t * 8 + j] = run;
        const int node = bucket * 2048 + t * 8 + j;
        if (node < N) rowstart[node] = run;
        run += loc[j];
    }
    __syncthreads();

    for (int i = beg + t; i < beg + total; i += 256) {
        const int p   = interm[i];
        const int pos = atomicAdd(&cnt[p >> 17], 1);
        csr[pos] = p & 0x1FFFF;
    }
}

// ---------------------------------------------------------------------------
// K_agg (R16/R18, unchanged): one wave per dst node; fp16 hW gather, f32
// accum; normalize + b_gat -> fp16 gout. R18 counters: 78 us, HBM 43%,
// VALU 55% — dual-bound.
// ---------------------------------------------------------------------------
__global__ __launch_bounds__(256) void k_agg(
    const int* __restrict__ rowstart, const int* __restrict__ csr,
    const float* __restrict__ aS, const float* __restrict__ aD,
    const __half* __restrict__ hWh, const float4* __restrict__ bgat4,
    __half* __restrict__ gout)
{
    const int t = threadIdx.x;
    const int w = t >> 6;
    const int n = blockIdx.x * 4 + w;
    const int lane = t & 63;
    const int slot = lane >> 3;      // 8 parallel edge slots
    const int cg   = lane & 7;       // colgroup: cols [cg*16, cg*16+16)
    const int head = cg >> 1;

    const int r0 = rowstart[n], r1 = rowstart[n + 1];
    const float adh = aD[n * 4 + head];

    float4 a0 = {0.f,0.f,0.f,0.f}, a1 = {0.f,0.f,0.f,0.f};
    float4 a2 = {0.f,0.f,0.f,0.f}, a3 = {0.f,0.f,0.f,0.f};
    float ss = 0.0f;

    if (slot == 0) {
        const float x0 = __expf(lrelu(aS[n * 4 + head] + adh));
        const float4* p0 = (const float4*)&hWh[(size_t)n * HID + cg * 16];
        const float4 q0 = p0[0], q1 = p0[1];
        acc16h(q0, q1, x0, a0, a1, a2, a3);
        ss += x0;
    }

    int j = r0 + slot;
    for (; j + 8 < r1; j += 16) {
        const int s0 = csr[j], s1 = csr[j + 8];
        const float x0 = __expf(lrelu(aS[s0 * 4 + head] + adh));
        const float x1 = __expf(lrelu(aS[s1 * 4 + head] + adh));
        const float4* p0 = (const float4*)&hWh[(size_t)s0 * HID + cg * 16];
        const float4* p1 = (const float4*)&hWh[(size_t)s1 * HID + cg * 16];
        const float4 q00 = p0[0], q01 = p0[1];
        const float4 q10 = p1[0], q11 = p1[1];
        acc16h(q00, q01, x0, a0, a1, a2, a3);
        acc16h(q10, q11, x1, a0, a1, a2, a3);
        ss += x0 + x1;
    }
    if (j < r1) {
        const int s0 = csr[j];
        const float x0 = __expf(lrelu(aS[s0 * 4 + head] + adh));
        const float4* p0 = (const float4*)&hWh[(size_t)s0 * HID + cg * 16];
        const float4 q0 = p0[0], q1 = p0[1];
        acc16h(q0, q1, x0, a0, a1, a2, a3);
        ss += x0;
    }

#pragma unroll
    for (int off = 8; off <= 32; off <<= 1) {
        a0.x += __shfl_xor(a0.x, off); a0.y += __shfl_xor(a0.y, off);
        a0.z += __shfl_xor(a0.z, off); a0.w += __shfl_xor(a0.w, off);
        a1.x += __shfl_xor(a1.x, off); a1.y += __shfl_xor(a1.y, off);
        a1.z += __shfl_xor(a1.z, off); a1.w += __shfl_xor(a1.w, off);
        a2.x += __shfl_xor(a2.x, off); a2.y += __shfl_xor(a2.y, off);
        a2.z += __shfl_xor(a2.z, off); a2.w += __shfl_xor(a2.w, off);
        a3.x += __shfl_xor(a3.x, off); a3.y += __shfl_xor(a3.y, off);
        a3.z += __shfl_xor(a3.z, off); a3.w += __shfl_xor(a3.w, off);
        ss += __shfl_xor(ss, off);
    }

    if (slot == 0) {
        const float inv = 1.0f / (ss + 1e-16f);
        const float4 bg0 = bgat4[cg * 4 + 0];
        const float4 bg1 = bgat4[cg * 4 + 1];
        const float4 bg2 = bgat4[cg * 4 + 2];
        const float4 bg3 = bgat4[cg * 4 + 3];
        const __half2 h0 = __float22half2_rn(make_float2(a0.x*inv+bg0.x, a0.y*inv+bg0.y));
        const __half2 h1 = __float22half2_rn(make_float2(a0.z*inv+bg0.z, a0.w*inv+bg0.w));
        const __half2 h2 = __float22half2_rn(make_float2(a1.x*inv+bg1.x, a1.y*inv+bg1.y));
        const __half2 h3 = __float22half2_rn(make_float2(a1.z*inv+bg1.z, a1.w*inv+bg1.w));
        const __half2 h4 = __float22half2_rn(make_float2(a2.x*inv+bg2.x, a2.y*inv+bg2.y));
        const __half2 h5 = __float22half2_rn(make_float2(a2.z*inv+bg2.z, a2.w*inv+bg2.w));
        const __half2 h6 = __float22half2_rn(make_float2(a3.x*inv+bg3.x, a3.y*inv+bg3.y));
        const __half2 h7 = __float22half2_rn(make_float2(a3.z*inv+bg3.z, a3.w*inv+bg3.w));
        uint4 p0, p1;
        p0.x = *(const unsigned*)&h0; p0.y = *(const unsigned*)&h1;
        p0.z = *(const unsigned*)&h2; p0.w = *(const unsigned*)&h3;
        p1.x = *(const unsigned*)&h4; p1.y = *(const unsigned*)&h5;
        p1.z = *(const unsigned*)&h6; p1.w = *(const unsigned*)&h7;
        __half* gp = &gout[(size_t)n * HID + cg * 16];
        *(uint4*)gp = p0;
        *(uint4*)(gp + 8) = p1;
    }
}

// ---------------------------------------------------------------------------
// k_mlp (R16, unchanged): MFMA MLP head.
// ---------------------------------------------------------------------------
__global__ __launch_bounds__(256) void k_mlp(
    const __half* __restrict__ gout, const __half* __restrict__ Wpk3,
    const float* __restrict__ b1, const float* __restrict__ W2,
    const float* __restrict__ b2, float2* __restrict__ out)
{
    const int t = threadIdx.x;
    const int w = t >> 6, lane = t & 63;
    const int l15 = lane & 15, g = lane >> 4;
    const int rowbase = blockIdx.x * 64 + w * 16;
    const int arow = rowbase + l15;
    const bool arok = (arow < N);

    f32x4 acc[4];
#pragma unroll
    for (int tt = 0; tt < 4; ++tt)
#pragma unroll
        for (int q = 0; q < 4; ++q) acc[tt][q] = 0.0f;

#pragma unroll
    for (int ks = 0; ks < 4; ++ks) {
        half8 a;
#pragma unroll
        for (int i = 0; i < 8; ++i) a[i] = (_Float16)0;
        if (arok) a = *(const half8*)&gout[(size_t)arow * HID + ks * 32 + g * 8];
        const half8* bp = (const half8*)&Wpk3[ks * 2048 + lane * 8];
#pragma unroll
        for (int tt = 0; tt < 4; ++tt)
            acc[tt] = __builtin_amdgcn_mfma_f32_16x16x32_f16(a, bp[tt * 64], acc[tt], 0, 0, 0);
    }

    float l0[4] = {0.f, 0.f, 0.f, 0.f}, l1[4] = {0.f, 0.f, 0.f, 0.f};
#pragma unroll
    for (int tt = 0; tt < 4; ++tt) {
        const int col = tt * 16 + l15;
        const float bv = b1[col];
        const float2 wv = *(const float2*)&W2[col * 2];
#pragma unroll
        for (int rg = 0; rg < 4; ++rg) {
            const float h2 = fmaxf(acc[tt][rg] + bv, 0.0f);
            l0[rg] = fmaf(h2, wv.x, l0[rg]);
            l1[rg] = fmaf(h2, wv.y, l1[rg]);
        }
    }
#pragma unroll
    for (int off = 1; off <= 8; off <<= 1) {
#pragma unroll
        for (int rg = 0; rg < 4; ++rg) {
            l0[rg] += __shfl_xor(l0[rg], off);
            l1[rg] += __shfl_xor(l1[rg], off);
        }
    }
    if (l15 == 0) {
        const float b20 = b2[0], b21 = b2[1];
#pragma unroll
        for (int rg = 0; rg < 4; ++rg) {
            const int row = rowbase + g * 4 + rg;
            if (row < N) out[row] = make_float2(l0[rg] + b20, l1[rg] + b21);
        }
    }
}

extern "C" void kernel_launch(void* const* d_in, const int* in_sizes, int n_in,
                              void* d_out, int out_size, void* d_ws, size_t ws_size,
                              hipStream_t stream) {
    const float* x     = (const float*)d_in[0];
    const int*   ei    = (const int*)d_in[1];
    const float* Win   = (const float*)d_in[2];
    const float* bin   = (const float*)d_in[3];
    const float* Wgat  = (const float*)d_in[4];
    const float* attS  = (const float*)d_in[5];
    const float* attD  = (const float*)d_in[6];
    const float* bgat  = (const float*)d_in[7];
    const float* W1    = (const float*)d_in[8];
    const float* b1    = (const float*)d_in[9];
    const float* W2    = (const float*)d_in[10];
    const float* b2    = (const float*)d_in[11];

    char* ws = (char*)d_ws;
    __half* hWh   = (__half*)(ws + HW_OFF);
    __half* gout  = (__half*)(ws + GOUT_OFF);
    int*   interm = (int*)(ws + GOUT_OFF);    // aliases gout; dead before k_agg
    float* aS     = (float*)(ws + ASRC_OFF);
    float* aD     = (float*)(ws + ADST_OFF);
    int*   row    = (int*)(ws + ROW_OFF);
    int*   bcnt   = (int*)(ws + BCNT_OFF);
    int*   bbase  = (int*)(ws + BBASE_OFF);
    __half* Wpk1  = (__half*)(ws + WPK1_OFF);
    __half* Wpk2  = (__half*)(ws + WPK2_OFF);
    __half* Wpk3  = (__half*)(ws + WPK3_OFF);
    int*   csr    = (int*)(ws + CSR_OFF);

    k_prep<<<192, 256, 0, stream>>>(Win, Wgat, W1, Wpk1, Wpk2, Wpk3, bcnt);
    k_proj<<<PROJ_NB, 256, 0, stream>>>(x, Wpk1, Wpk2, bin, attS, attD,
                                        hWh, aS, aD);
    k_binA<<<BIN_NB, 256, 0, stream>>>(ei, bcnt, interm);
    k_scanB<<<1, 64, 0, stream>>>(bcnt, bbase, row);
    k_binB<<<NBUCK, 256, 0, stream>>>(interm, bcnt, bbase, row, csr);
    k_agg<<<N / 4, 256, 0, stream>>>(row, csr, aS, aD, hWh,
                                     (const float4*)bgat, gout);
    k_mlp<<<MLP_NB, 256, 0, stream>>>(gout, Wpk3, b1, W2, b2, (float2*)d_out);
}

// Round 11
// 344.220 us; speedup vs baseline: 1.1756x; 1.0226x over previous
//
#include <hip/hip_runtime.h>
#include <hip/hip_fp16.h>

#define DEVFN __device__ __forceinline__

constexpr int N    = 100000;
constexpr int F_IN = 166;
constexpr int HID  = 128;
constexpr int E    = 1600000;

using half8 = __attribute__((ext_vector_type(8))) _Float16;
using f32x4 = __attribute__((ext_vector_type(4))) float;

// ---- workspace layout (bytes, all 16B-aligned; ends 62.1 MB as before) ----
constexpr size_t HW_OFF   = 0;            // hW [N,128] fp16      25.6 MB
constexpr size_t GOUT_OFF = 25600000;     // GAT out [N,128] fp16 25.6 MB; ALIASED by
                                          //   interm [49*40960] i32 8.03 MB during CSR build
constexpr size_t ASRC_OFF = 51200000;     // a_src [N,4] f32       1.6 MB
constexpr size_t ADST_OFF = 52800000;     // a_dst [N,4] f32       1.6 MB
constexpr size_t ROW_OFF  = 54800000;     // rowstart [N+1] i32 (ends 55,200,004)
constexpr size_t BCNT_OFF = 55200016;     // bucket counters [49] i32 (zeroed in k_prep)
constexpr size_t WPK1_OFF = 55600544;     // Win  packed fp16 frags 49,152 B
constexpr size_t WPK2_OFF = 55649696;     // Wgat packed fp16 frags 32,768 B
constexpr size_t WPK3_OFF = 55682464;     // W1   packed fp16 frags 16,384 B
constexpr size_t CSR_OFF  = 55700000;     // csr_src [E] i32       6.4 MB

// R21: k_proj keeps the R18 geometry (64 rows; R19 lesson: bigger tiles
// regress — latency-bound, occupancy wins). binA FUSED into k_proj's tail
// (hidden under its 26%-occupancy latency stalls; dense per-block ranges, so
// no R17-style atomic line ping-pong). scanB folded into binB. 7->5 kernels.
constexpr int PROJ_ROWS  = 64;
constexpr int PROJ_NB    = (N + PROJ_ROWS - 1) / PROJ_ROWS;    // 1563
constexpr int MLP_NB     = (N + 63) / 64;                      // 1563
constexpr int EPB        = 1024;   // edges binned per k_proj block (1563*1024 >= E)

constexpr int NBUCK     = 49;
constexpr int BCAP      = 40960;

DEVFN float lrelu(float e) { return e > 0.0f ? e : 0.2f * e; }

// 8 half-precision messages (float4 raw) fma'd into 2 float4 f32 accs.
// R21 k_agg geometry: slot(4) x cg(16), 8 cols/lane — reduce is 2 stages x 9
// values (was 3 x 17 = 102 VALU ops, ~60% of the lane budget at R20's
// VALU 55%). Same f32 accumulate; loads stay 16B/lane coalesced.
DEVFN void acc8h(const float4& q, const float x, float4& a0, float4& a1)
{
    const __half2* h = (const __half2*)&q;
    a0.x = fmaf(__low2float(h[0]),  x, a0.x);
    a0.y = fmaf(__high2float(h[0]), x, a0.y);
    a0.z = fmaf(__low2float(h[1]),  x, a0.z);
    a0.w = fmaf(__high2float(h[1]), x, a0.w);
    a1.x = fmaf(__low2float(h[2]),  x, a1.x);
    a1.y = fmaf(__high2float(h[2]), x, a1.y);
    a1.z = fmaf(__low2float(h[3]),  x, a1.z);
    a1.w = fmaf(__high2float(h[3]), x, a1.w);
}

// ---------------------------------------------------------------------------
// k_prep: pack Win/Wgat/W1 into fp16 MFMA B-fragment layout + zero bcnt.
// ---------------------------------------------------------------------------
__global__ __launch_bounds__(256) void k_prep(const float* __restrict__ Win,
                                              const float* __restrict__ Wgat,
                                              const float* __restrict__ W1,
                                              __half* __restrict__ Wpk1,
                                              __half* __restrict__ Wpk2,
                                              __half* __restrict__ Wpk3,
                                              int* __restrict__ bcnt)
{
    const int idx = blockIdx.x * 256 + threadIdx.x;
    if (idx < NBUCK) bcnt[idx] = 0;
    if (idx < 24576) {                                  // GEMM1: 6 ks * 8 t
        const int i  = idx & 7;
        const int l  = (idx >> 3) & 63;
        const int tt = (idx >> 9) & 7;
        const int ks = idx >> 12;
        const int k   = ks * 32 + (l >> 4) * 8 + i;
        const int col = tt * 16 + (l & 15);
        const float v = (k < F_IN) ? Win[k * HID + col] : 0.0f;
        Wpk1[idx] = __float2half(v);
    } else if (idx < 40960) {                           // GEMM2: 4 ks * 8 t
        const int j  = idx - 24576;
        const int i  = j & 7;
        const int l  = (j >> 3) & 63;
        const int tt = (j >> 9) & 7;
        const int ks = j >> 12;
        const int k   = ks * 32 + (l >> 4) * 8 + i;
        const int col = tt * 16 + (l & 15);
        Wpk2[j] = __float2half(Wgat[k * HID + col]);
    } else {                                            // MLP W1: 4 ks * 4 t
        const int j  = idx - 40960;
        const int i  = j & 7;
        const int l  = (j >> 3) & 63;
        const int tt = (j >> 9) & 3;
        const int ks = j >> 11;
        const int k   = ks * 32 + (l >> 4) * 8 + i;
        const int col = tt * 16 + (l & 15);
        Wpk3[j] = __float2half(W1[k * 64 + col]);
    }
}

// ---------------------------------------------------------------------------
// k_proj (R18 geometry + R21 fused edge-binning tail): MFMA, 64 rows/block,
// 4 waves x 16 rows, 8 col-tiles. C/D col=lane&15, row=(lane>>4)*4+reg
// (m89/m91). Tail: bin 1024 edges/block into 49 fixed-capacity dst-buckets
// (LDS hist reusing sh -> 49 global reserves -> dense per-(block,bucket)
// consecutive interm writes).
// ---------------------------------------------------------------------------
__global__ __launch_bounds__(256) void k_proj(
    const float* __restrict__ x,
    const __half* __restrict__ Wpk1, const __half* __restrict__ Wpk2,
    const float* __restrict__ bin,
    const float* __restrict__ attS, const float* __restrict__ attD,
    __half* __restrict__ hWh, float* __restrict__ aS, float* __restrict__ aD,
    const int* __restrict__ ei, int* __restrict__ bcnt,
    int* __restrict__ interm)
{
    __shared__ __align__(16) __half sh[PROJ_ROWS * 200];   // 25600 B

    const int t    = threadIdx.x;
    const int row0 = blockIdx.x * PROJ_ROWS;
    const int w    = t >> 6;
    const int lane = t & 63;
    const int l15  = lane & 15;
    const int g    = lane >> 4;
    const int arow = w * 16 + l15;

    for (int idx = t; idx < PROJ_ROWS * 100; idx += 256) {
        const int r   = idx / 100;
        const int kk2 = (idx - r * 100) * 2;
        float2 v = make_float2(0.f, 0.f);
        const int row = row0 + r;
        if (row < N && kk2 < F_IN)
            v = *(const float2*)&x[(size_t)row * F_IN + kk2];
        *(__half2*)&sh[r * 200 + kk2] = __float22half2_rn(v);
    }
    __syncthreads();

    f32x4 acc[8];
#pragma unroll
    for (int tt = 0; tt < 8; ++tt)
#pragma unroll
        for (int q = 0; q < 4; ++q) acc[tt][q] = 0.0f;

#pragma unroll
    for (int ks = 0; ks < 6; ++ks) {
        const half8 a = *(const half8*)&sh[arow * 200 + ks * 32 + g * 8];
        const half8* bp = (const half8*)&Wpk1[ks * 4096 + lane * 8];
#pragma unroll
        for (int tt = 0; tt < 8; ++tt) {
            acc[tt] = __builtin_amdgcn_mfma_f32_16x16x32_f16(a, bp[tt * 64], acc[tt], 0, 0, 0);
        }
    }

    __syncthreads();

#pragma unroll
    for (int tt = 0; tt < 8; ++tt) {
        const int col = tt * 16 + l15;
        const float bv = bin[col];
#pragma unroll
        for (int rg = 0; rg < 4; ++rg) {
            const int r = w * 16 + g * 4 + rg;
            sh[r * 136 + col] = __float2half(fmaxf(acc[tt][rg] + bv, 0.0f));
        }
    }
    __syncthreads();

#pragma unroll
    for (int tt = 0; tt < 8; ++tt)
#pragma unroll
        for (int q = 0; q < 4; ++q) acc[tt][q] = 0.0f;

#pragma unroll
    for (int ks = 0; ks < 4; ++ks) {
        const half8 a = *(const half8*)&sh[arow * 136 + ks * 32 + g * 8];
        const half8* bp = (const half8*)&Wpk2[ks * 4096 + lane * 8];
#pragma unroll
        for (int tt = 0; tt < 8; ++tt) {
            acc[tt] = __builtin_amdgcn_mfma_f32_16x16x32_f16(a, bp[tt * 64], acc[tt], 0, 0, 0);
        }
    }

    const int grow0 = row0 + w * 16 + g * 4;
    float asv[8], adv[8];
#pragma unroll
    for (int tt = 0; tt < 8; ++tt) {
        asv[tt] = attS[tt * 16 + l15];
        adv[tt] = attD[tt * 16 + l15];
    }
    float psb[4][4], pdb[4][4];
#pragma unroll
    for (int rg = 0; rg < 4; ++rg) {
#pragma unroll
        for (int h = 0; h < 4; ++h) {
            float ps = acc[2*h][rg] * asv[2*h] + acc[2*h+1][rg] * asv[2*h+1];
            float pd = acc[2*h][rg] * adv[2*h] + acc[2*h+1][rg] * adv[2*h+1];
#pragma unroll
            for (int off = 1; off <= 8; off <<= 1) {
                ps += __shfl_xor(ps, off);
                pd += __shfl_xor(pd, off);
            }
            psb[rg][h] = ps; pdb[rg][h] = pd;
        }
    }
    if (l15 == 0) {
#pragma unroll
        for (int rg = 0; rg < 4; ++rg) {
            const int row = grow0 + rg;
            if (row < N) {
                *(float4*)&aS[row * 4] = make_float4(psb[rg][0], psb[rg][1], psb[rg][2], psb[rg][3]);
                *(float4*)&aD[row * 4] = make_float4(pdb[rg][0], pdb[rg][1], pdb[rg][2], pdb[rg][3]);
            }
        }
    }

    __syncthreads();
#pragma unroll
    for (int tt = 0; tt < 8; ++tt) {
        const int col = tt * 16 + l15;
#pragma unroll
        for (int rg = 0; rg < 4; ++rg) {
            const int r = w * 16 + g * 4 + rg;
            sh[r * 136 + col] = __float2half(acc[tt][rg]);
        }
    }
    __syncthreads();
    for (int idx = t; idx < PROJ_ROWS * 16; idx += 256) {
        const int r  = idx >> 4;
        const int c8 = idx & 15;
        const int row = row0 + r;
        if (row < N) {
            const uint4 v = *(const uint4*)&sh[r * 136 + c8 * 8];
            *(uint4*)&hWh[(size_t)row * HID + c8 * 8] = v;
        }
    }

    // ---- fused edge-binning tail (was k_binA) ----
    __syncthreads();                    // done reading sh; reuse as int scratch
    int* hist  = (int*)sh;              // [64]
    int* basep = hist + 64;             // [64]
    int* offp  = hist + 128;            // [64]
    if (t < NBUCK) hist[t] = 0;
    __syncthreads();

    const int e0 = blockIdx.x * EPB;
    int pk[4], bk[4];
#pragma unroll
    for (int j = 0; j < 4; ++j) {
        const int i = e0 + j * 256 + t;
        bk[j] = -1;
        if (i < E) {
            const int s = ei[i], d = ei[E + i];
            const int b = d >> 11;
            bk[j] = b;
            pk[j] = s | ((d & 2047) << 17);
            atomicAdd(&hist[b], 1);
        }
    }
    __syncthreads();
    if (t < NBUCK) { basep[t] = atomicAdd(&bcnt[t], hist[t]); offp[t] = 0; }
    __syncthreads();
#pragma unroll
    for (int j = 0; j < 4; ++j) {
        if (bk[j] >= 0) {
            const int p   = atomicAdd(&offp[bk[j]], 1);
            const int pos = basep[bk[j]] + p;
            if (pos < BCAP) interm[bk[j] * BCAP + pos] = pk[j];
        }
    }
}

// ---------------------------------------------------------------------------
// k_binB (R19 + folded scanB): one wg per bucket. First-wave 49-value reduce
// gives the bucket base; LDS degree count (2048 cursors) -> in-LDS prefix ->
// dense rowstart write -> LDS-cursor scatter to exclusive csr window.
// ---------------------------------------------------------------------------
__global__ __launch_bounds__(256) void k_binB(const int* __restrict__ interm,
                                              const int* __restrict__ bcnt,
                                              int* __restrict__ rowstart,
                                              int* __restrict__ csr)
{
    __shared__ int cnt[2048];
    __shared__ int wsum[256];
    __shared__ int sbase;
    const int t      = threadIdx.x;
    const int bucket = blockIdx.x;

    if (t < 64) {                       // exclusive prefix for OUR bucket
        int v = (t < NBUCK && t < bucket) ? min(bcnt[t], BCAP) : 0;
#pragma unroll
        for (int off = 32; off >= 1; off >>= 1) v += __shfl_xor(v, off);
        if (t == 0) sbase = v;
    }
    if (bucket == 0 && t == 0) rowstart[N] = E;
    for (int i = t; i < 2048; i += 256) cnt[i] = 0;
    __syncthreads();

    const int total = min(bcnt[bucket], BCAP);
    const int beg   = bucket * BCAP;
    for (int i = beg + t; i < beg + total; i += 256)
        atomicAdd(&cnt[interm[i] >> 17], 1);
    __syncthreads();

    int loc[8];
    int s = 0;
#pragma unroll
    for (int j = 0; j < 8; ++j) { loc[j] = cnt[t * 8 + j]; s += loc[j]; }
    wsum[t] = s;
    __syncthreads();
    for (int off = 1; off < 256; off <<= 1) {
        const int v = (t >= off) ? wsum[t - off] : 0;
        __syncthreads();
        wsum[t] += v;
        __syncthreads();
    }
    int run = sbase + wsum[t] - s;
#pragma unroll
    for (int j = 0; j < 8; ++j) {
        cnt[t * 8 + j] = run;
        const int node = bucket * 2048 + t * 8 + j;
        if (node < N) rowstart[node] = run;
        run += loc[j];
    }
    __syncthreads();

    for (int i = beg + t; i < beg + total; i += 256) {
        const int p   = interm[i];
        const int pos = atomicAdd(&cnt[p >> 17], 1);
        csr[pos] = p & 0x1FFFF;
    }
}

// ---------------------------------------------------------------------------
// K_agg R21: one wave per dst node; lane = slot(4) x cg(16), 8 cols/lane.
// fp16 hW gather (v_fma_mix, f32 accum). Slot-reduce now 2 stages x 9 values
// (was 3 x 17 — the dominant VALU term at R20's 55% VALUBusy).
// ---------------------------------------------------------------------------
__global__ __launch_bounds__(256) void k_agg(
    const int* __restrict__ rowstart, const int* __restrict__ csr,
    const float* __restrict__ aS, const float* __restrict__ aD,
    const __half* __restrict__ hWh, const float4* __restrict__ bgat4,
    __half* __restrict__ gout)
{
    const int t = threadIdx.x;
    const int w = t >> 6;
    const int n = blockIdx.x * 4 + w;
    const int lane = t & 63;
    const int slot = lane >> 4;      // 4 parallel edge slots
    const int cg   = lane & 15;      // colgroup: cols [cg*8, cg*8+8)
    const int head = cg >> 2;

    const int r0 = rowstart[n], r1 = rowstart[n + 1];
    const float adh = aD[n * 4 + head];

    float4 a0 = {0.f,0.f,0.f,0.f}, a1 = {0.f,0.f,0.f,0.f};
    float ss = 0.0f;

    // self-loop: processed once (by slot-0 lanes), reduced with the rest
    if (slot == 0) {
        const float x0 = __expf(lrelu(aS[n * 4 + head] + adh));
        const float4 q = *(const float4*)&hWh[(size_t)n * HID + cg * 8];
        acc8h(q, x0, a0, a1);
        ss += x0;
    }

    int j = r0 + slot;
    for (; j + 4 < r1; j += 8) {
        const int s0 = csr[j], s1 = csr[j + 4];
        const float x0 = __expf(lrelu(aS[s0 * 4 + head] + adh));
        const float x1 = __expf(lrelu(aS[s1 * 4 + head] + adh));
        const float4 q0 = *(const float4*)&hWh[(size_t)s0 * HID + cg * 8];
        const float4 q1 = *(const float4*)&hWh[(size_t)s1 * HID + cg * 8];
        acc8h(q0, x0, a0, a1);
        acc8h(q1, x1, a0, a1);
        ss += x0 + x1;
    }
    if (j < r1) {
        const int s0 = csr[j];
        const float x0 = __expf(lrelu(aS[s0 * 4 + head] + adh));
        const float4 q = *(const float4*)&hWh[(size_t)s0 * HID + cg * 8];
        acc8h(q, x0, a0, a1);
        ss += x0;
    }

    // reduce across the 4 edge-slots (lane bits 4..5)
#pragma unroll
    for (int off = 16; off <= 32; off <<= 1) {
        a0.x += __shfl_xor(a0.x, off); a0.y += __shfl_xor(a0.y, off);
        a0.z += __shfl_xor(a0.z, off); a0.w += __shfl_xor(a0.w, off);
        a1.x += __shfl_xor(a1.x, off); a1.y += __shfl_xor(a1.y, off);
        a1.z += __shfl_xor(a1.z, off); a1.w += __shfl_xor(a1.w, off);
        ss += __shfl_xor(ss, off);
    }

    // slot-0 lanes own 8 cols each: normalize, +b_gat, fp16 store to gout
    if (slot == 0) {
        const float inv = 1.0f / (ss + 1e-16f);
        const float4 bg0 = bgat4[cg * 2 + 0];
        const float4 bg1 = bgat4[cg * 2 + 1];
        const __half2 h0 = __float22half2_rn(make_float2(a0.x*inv+bg0.x, a0.y*inv+bg0.y));
        const __half2 h1 = __float22half2_rn(make_float2(a0.z*inv+bg0.z, a0.w*inv+bg0.w));
        const __half2 h2 = __float22half2_rn(make_float2(a1.x*inv+bg1.x, a1.y*inv+bg1.y));
        const __half2 h3 = __float22half2_rn(make_float2(a1.z*inv+bg1.z, a1.w*inv+bg1.w));
        uint4 p;
        p.x = *(const unsigned*)&h0; p.y = *(const unsigned*)&h1;
        p.z = *(const unsigned*)&h2; p.w = *(const unsigned*)&h3;
        *(uint4*)&gout[(size_t)n * HID + cg * 8] = p;
    }
}

// ---------------------------------------------------------------------------
// k_mlp (R16, unchanged): MFMA MLP head.
// ---------------------------------------------------------------------------
__global__ __launch_bounds__(256) void k_mlp(
    const __half* __restrict__ gout, const __half* __restrict__ Wpk3,
    const float* __restrict__ b1, const float* __restrict__ W2,
    const float* __restrict__ b2, float2* __restrict__ out)
{
    const int t = threadIdx.x;
    const int w = t >> 6, lane = t & 63;
    const int l15 = lane & 15, g = lane >> 4;
    const int rowbase = blockIdx.x * 64 + w * 16;
    const int arow = rowbase + l15;
    const bool arok = (arow < N);

    f32x4 acc[4];
#pragma unroll
    for (int tt = 0; tt < 4; ++tt)
#pragma unroll
        for (int q = 0; q < 4; ++q) acc[tt][q] = 0.0f;

#pragma unroll
    for (int ks = 0; ks < 4; ++ks) {
        half8 a;
#pragma unroll
        for (int i = 0; i < 8; ++i) a[i] = (_Float16)0;
        if (arok) a = *(const half8*)&gout[(size_t)arow * HID + ks * 32 + g * 8];
        const half8* bp = (const half8*)&Wpk3[ks * 2048 + lane * 8];
#pragma unroll
        for (int tt = 0; tt < 4; ++tt)
            acc[tt] = __builtin_amdgcn_mfma_f32_16x16x32_f16(a, bp[tt * 64], acc[tt], 0, 0, 0);
    }

    float l0[4] = {0.f, 0.f, 0.f, 0.f}, l1[4] = {0.f, 0.f, 0.f, 0.f};
#pragma unroll
    for (int tt = 0; tt < 4; ++tt) {
        const int col = tt * 16 + l15;
        const float bv = b1[col];
        const float2 wv = *(const float2*)&W2[col * 2];
#pragma unroll
        for (int rg = 0; rg < 4; ++rg) {
            const float h2 = fmaxf(acc[tt][rg] + bv, 0.0f);
            l0[rg] = fmaf(h2, wv.x, l0[rg]);
            l1[rg] = fmaf(h2, wv.y, l1[rg]);
        }
    }
#pragma unroll
    for (int off = 1; off <= 8; off <<= 1) {
#pragma unroll
        for (int rg = 0; rg < 4; ++rg) {
            l0[rg] += __shfl_xor(l0[rg], off);
            l1[rg] += __shfl_xor(l1[rg], off);
        }
    }
    if (l15 == 0) {
        const float b20 = b2[0], b21 = b2[1];
#pragma unroll
        for (int rg = 0; rg < 4; ++rg) {
            const int row = rowbase + g * 4 + rg;
            if (row < N) out[row] = make_float2(l0[rg] + b20, l1[rg] + b21);
        }
    }
}

extern "C" void kernel_launch(void* const* d_in, const int* in_sizes, int n_in,
                              void* d_out, int out_size, void* d_ws, size_t ws_size,
                              hipStream_t stream) {
    const float* x     = (const float*)d_in[0];
    const int*   ei    = (const int*)d_in[1];
    const float* Win   = (const float*)d_in[2];
    const float* bin   = (const float*)d_in[3];
    const float* Wgat  = (const float*)d_in[4];
    const float* attS  = (const float*)d_in[5];
    const float* attD  = (const float*)d_in[6];
    const float* bgat  = (const float*)d_in[7];
    const float* W1    = (const float*)d_in[8];
    const float* b1    = (const float*)d_in[9];
    const float* W2    = (const float*)d_in[10];
    const float* b2    = (const float*)d_in[11];

    char* ws = (char*)d_ws;
    __half* hWh   = (__half*)(ws + HW_OFF);
    __half* gout  = (__half*)(ws + GOUT_OFF);
    int*   interm = (int*)(ws + GOUT_OFF);    // aliases gout; dead before k_agg
    float* aS     = (float*)(ws + ASRC_OFF);
    float* aD     = (float*)(ws + ADST_OFF);
    int*   row    = (int*)(ws + ROW_OFF);
    int*   bcnt   = (int*)(ws + BCNT_OFF);
    __half* Wpk1  = (__half*)(ws + WPK1_OFF);
    __half* Wpk2  = (__half*)(ws + WPK2_OFF);
    __half* Wpk3  = (__half*)(ws + WPK3_OFF);
    int*   csr    = (int*)(ws + CSR_OFF);

    k_prep<<<192, 256, 0, stream>>>(Win, Wgat, W1, Wpk1, Wpk2, Wpk3, bcnt);
    k_proj<<<PROJ_NB, 256, 0, stream>>>(x, Wpk1, Wpk2, bin, attS, attD,
                                        hWh, aS, aD, ei, bcnt, interm);
    k_binB<<<NBUCK, 256, 0, stream>>>(interm, bcnt, row, csr);
    k_agg<<<N / 4, 256, 0, stream>>>(row, csr, aS, aD, hWh,
                                     (const float4*)bgat, gout);
    k_mlp<<<MLP_NB, 256, 0, stream>>>(gout, Wpk3, b1, W2, b2, (float2*)d_out);
}

// Round 12
// 280.507 us; speedup vs baseline: 1.4426x; 1.2271x over previous
//
#include <hip/hip_runtime.h>
#include <hip/hip_fp16.h>

#define DEVFN __device__ __forceinline__

constexpr int N    = 100000;
constexpr int F_IN = 166;
constexpr int HID  = 128;
constexpr int E    = 1600000;

using half8 = __attribute__((ext_vector_type(8))) _Float16;
using f32x4 = __attribute__((ext_vector_type(4))) float;

// ---- workspace layout (bytes, all 16B-aligned; ends 62.1 MB as before) ----
constexpr size_t HW_OFF   = 0;            // hW [N,128] fp16      25.6 MB
constexpr size_t GOUT_OFF = 25600000;     // GAT out [N,128] fp16 25.6 MB; ALIASED by
                                          //   interm [49*40960] i32 8.03 MB during CSR build
constexpr size_t ASRC_OFF = 51200000;     // a_src [N,4] f32       1.6 MB
constexpr size_t ADST_OFF = 52800000;     // a_dst [N,4] f32       1.6 MB
constexpr size_t ROW_OFF  = 54800000;     // rowstart [N+1] i32 (ends 55,200,004)
constexpr size_t BCNT_OFF = 55200016;     // bucket counters [49] i32 (zeroed in k_prep)
constexpr size_t WPK1_OFF = 55600544;     // Win  packed fp16 frags 49,152 B
constexpr size_t WPK2_OFF = 55649696;     // Wgat packed fp16 frags 32,768 B
constexpr size_t WPK3_OFF = 55682464;     // W1   packed fp16 frags 16,384 B
constexpr size_t CSR_OFF  = 55700000;     // csr_src [E] i32       6.4 MB

// R22 k_proj geometry: 64 rows/block, 512 threads = 8 waves:
// wave = (rowgroup 0-3) x (colgroup 0-1), 4 col-tiles/wave. Same 25.6 KB LDS
// and MFMA count, but 2x waves per LDS allocation (R21 counters: 93us at
// occupancy 25%, MfmaUtil 3.2% — latency-bound; wave count was the cap).
// R19 lesson (bigger ROW tiles kill occupancy) untouched — rows stay 64.
constexpr int PROJ_ROWS  = 64;
constexpr int PROJ_NB    = (N + PROJ_ROWS - 1) / PROJ_ROWS;    // 1563
constexpr int MLP_NB     = (N + 63) / 64;                      // 1563
constexpr int EPB        = 1024;   // edges binned per k_proj block

constexpr int NBUCK     = 49;
constexpr int BCAP      = 40960;

DEVFN float lrelu(float e) { return e > 0.0f ? e : 0.2f * e; }

// 8 half-precision messages (float4 raw) fma'd into 2 float4 f32 accs.
DEVFN void acc8h(const float4& q, const float x, float4& a0, float4& a1)
{
    const __half2* h = (const __half2*)&q;
    a0.x = fmaf(__low2float(h[0]),  x, a0.x);
    a0.y = fmaf(__high2float(h[0]), x, a0.y);
    a0.z = fmaf(__low2float(h[1]),  x, a0.z);
    a0.w = fmaf(__high2float(h[1]), x, a0.w);
    a1.x = fmaf(__low2float(h[2]),  x, a1.x);
    a1.y = fmaf(__high2float(h[2]), x, a1.y);
    a1.z = fmaf(__low2float(h[3]),  x, a1.z);
    a1.w = fmaf(__high2float(h[3]), x, a1.w);
}

// ---------------------------------------------------------------------------
// k_prep: pack Win/Wgat/W1 into fp16 MFMA B-fragment layout + zero bcnt.
// ---------------------------------------------------------------------------
__global__ __launch_bounds__(256) void k_prep(const float* __restrict__ Win,
                                              const float* __restrict__ Wgat,
                                              const float* __restrict__ W1,
                                              __half* __restrict__ Wpk1,
                                              __half* __restrict__ Wpk2,
                                              __half* __restrict__ Wpk3,
                                              int* __restrict__ bcnt)
{
    const int idx = blockIdx.x * 256 + threadIdx.x;
    if (idx < NBUCK) bcnt[idx] = 0;
    if (idx < 24576) {                                  // GEMM1: 6 ks * 8 t
        const int i  = idx & 7;
        const int l  = (idx >> 3) & 63;
        const int tt = (idx >> 9) & 7;
        const int ks = idx >> 12;
        const int k   = ks * 32 + (l >> 4) * 8 + i;
        const int col = tt * 16 + (l & 15);
        const float v = (k < F_IN) ? Win[k * HID + col] : 0.0f;
        Wpk1[idx] = __float2half(v);
    } else if (idx < 40960) {                           // GEMM2: 4 ks * 8 t
        const int j  = idx - 24576;
        const int i  = j & 7;
        const int l  = (j >> 3) & 63;
        const int tt = (j >> 9) & 7;
        const int ks = j >> 12;
        const int k   = ks * 32 + (l >> 4) * 8 + i;
        const int col = tt * 16 + (l & 15);
        Wpk2[j] = __float2half(Wgat[k * HID + col]);
    } else {                                            // MLP W1: 4 ks * 4 t
        const int j  = idx - 40960;
        const int i  = j & 7;
        const int l  = (j >> 3) & 63;
        const int tt = (j >> 9) & 3;
        const int ks = j >> 11;
        const int k   = ks * 32 + (l >> 4) * 8 + i;
        const int col = tt * 16 + (l & 15);
        Wpk3[j] = __float2half(W1[k * 64 + col]);
    }
}

// ---------------------------------------------------------------------------
// k_proj R22: 512 threads / 8 waves. Wave w: rowgroup rg4=w&3 (rows rg4*16..
// +16), colgroup cgr=w>>2 (col-tiles cgr*4..cgr*4+4). acc[4] f32x4 (16 regs,
// was 32). C/D col=lane&15, row=(lane>>4)*4+reg (m89/m91). aS/aD computed
// post-restage from fp16 hW in LDS (8 threads/row, pair-shfl per head).
// Tail: fused edge binning (R21) — dense per-(block,bucket) interm ranges.
// ---------------------------------------------------------------------------
__global__ __launch_bounds__(512) void k_proj(
    const float* __restrict__ x,
    const __half* __restrict__ Wpk1, const __half* __restrict__ Wpk2,
    const float* __restrict__ bin,
    const float* __restrict__ attS, const float* __restrict__ attD,
    __half* __restrict__ hWh, float* __restrict__ aS, float* __restrict__ aD,
    const int* __restrict__ ei, int* __restrict__ bcnt,
    int* __restrict__ interm)
{
    __shared__ __align__(16) __half sh[PROJ_ROWS * 200];   // 25600 B

    const int t    = threadIdx.x;
    const int row0 = blockIdx.x * PROJ_ROWS;
    const int w    = t >> 6;
    const int lane = t & 63;
    const int l15  = lane & 15;
    const int g    = lane >> 4;
    const int rg4  = w & 3;           // rowgroup
    const int cgr  = w >> 2;          // colgroup (0: cols 0-63, 1: 64-127)
    const int arow = rg4 * 16 + l15;

    for (int idx = t; idx < PROJ_ROWS * 100; idx += 512) {
        const int r   = idx / 100;
        const int kk2 = (idx - r * 100) * 2;
        float2 v = make_float2(0.f, 0.f);
        const int row = row0 + r;
        if (row < N && kk2 < F_IN)
            v = *(const float2*)&x[(size_t)row * F_IN + kk2];
        *(__half2*)&sh[r * 200 + kk2] = __float22half2_rn(v);
    }
    __syncthreads();

    f32x4 acc[4];
#pragma unroll
    for (int tt = 0; tt < 4; ++tt)
#pragma unroll
        for (int q = 0; q < 4; ++q) acc[tt][q] = 0.0f;

    // ---- GEMM1: h = relu(x @ Win + bin); K padded to 192, 6 K-steps ----
#pragma unroll
    for (int ks = 0; ks < 6; ++ks) {
        const half8 a = *(const half8*)&sh[arow * 200 + ks * 32 + g * 8];
        const half8* bp = (const half8*)&Wpk1[ks * 4096 + cgr * 2048 + lane * 8];
#pragma unroll
        for (int tt = 0; tt < 4; ++tt) {
            acc[tt] = __builtin_amdgcn_mfma_f32_16x16x32_f16(a, bp[tt * 64], acc[tt], 0, 0, 0);
        }
    }

    __syncthreads();

    // ---- epilogue 1: h = relu(acc + bin) -> fp16 LDS, stride 136 ----
#pragma unroll
    for (int tt = 0; tt < 4; ++tt) {
        const int col = (cgr * 4 + tt) * 16 + l15;
        const float bv = bin[col];
#pragma unroll
        for (int rg = 0; rg < 4; ++rg) {
            const int r = rg4 * 16 + g * 4 + rg;
            sh[r * 136 + col] = __float2half(fmaxf(acc[tt][rg] + bv, 0.0f));
        }
    }
    __syncthreads();

#pragma unroll
    for (int tt = 0; tt < 4; ++tt)
#pragma unroll
        for (int q = 0; q < 4; ++q) acc[tt][q] = 0.0f;

    // ---- GEMM2: hW = h @ Wgat; K = 128, 4 K-steps ----
#pragma unroll
    for (int ks = 0; ks < 4; ++ks) {
        const half8 a = *(const half8*)&sh[arow * 136 + ks * 32 + g * 8];
        const half8* bp = (const half8*)&Wpk2[ks * 4096 + cgr * 2048 + lane * 8];
#pragma unroll
        for (int tt = 0; tt < 4; ++tt) {
            acc[tt] = __builtin_amdgcn_mfma_f32_16x16x32_f16(a, bp[tt * 64], acc[tt], 0, 0, 0);
        }
    }

    // ---- restage hW (fp16) into sh, stride 136 ----
    __syncthreads();   // all waves done reading h-tile
#pragma unroll
    for (int tt = 0; tt < 4; ++tt) {
        const int col = (cgr * 4 + tt) * 16 + l15;
#pragma unroll
        for (int rg = 0; rg < 4; ++rg) {
            const int r = rg4 * 16 + g * 4 + rg;
            sh[r * 136 + col] = __float2half(acc[tt][rg]);
        }
    }
    __syncthreads();

    // ---- aS/aD from LDS hW (8 threads/row: 16 cols each; head = c8>>1) ----
    {
        const int r2   = t >> 3;        // 0..63
        const int c8   = t & 7;
        const int head = c8 >> 1;
        float ps = 0.0f, pd = 0.0f;
#pragma unroll
        for (int k2 = 0; k2 < 8; ++k2) {
            const int col = c8 * 16 + k2 * 2;
            const __half2 hv = *(const __half2*)&sh[r2 * 136 + col];
            const float v0 = __low2float(hv), v1 = __high2float(hv);
            ps = fmaf(v0, attS[col], fmaf(v1, attS[col + 1], ps));
            pd = fmaf(v0, attD[col], fmaf(v1, attD[col + 1], pd));
        }
        ps += __shfl_xor(ps, 1);
        pd += __shfl_xor(pd, 1);
        const int row = row0 + r2;
        if (!(c8 & 1) && row < N) {
            aS[row * 4 + head] = ps;
            aD[row * 4 + head] = pd;
        }
    }

    // ---- hW coalesced global store ----
    for (int idx = t; idx < PROJ_ROWS * 16; idx += 512) {
        const int r  = idx >> 4;
        const int c8 = idx & 15;
        const int row = row0 + r;
        if (row < N) {
            const uint4 v = *(const uint4*)&sh[r * 136 + c8 * 8];
            *(uint4*)&hWh[(size_t)row * HID + c8 * 8] = v;
        }
    }

    // ---- fused edge-binning tail (was k_binA) ----
    __syncthreads();                    // done reading sh; reuse as int scratch
    int* hist  = (int*)sh;              // [64]
    int* basep = hist + 64;             // [64]
    int* offp  = hist + 128;            // [64]
    if (t < NBUCK) hist[t] = 0;
    __syncthreads();

    const int e0 = blockIdx.x * EPB;
    int pk[2], bk[2];
#pragma unroll
    for (int j = 0; j < 2; ++j) {
        const int i = e0 + j * 512 + t;
        bk[j] = -1;
        if (i < E) {
            const int s = ei[i], d = ei[E + i];
            const int b = d >> 11;
            bk[j] = b;
            pk[j] = s | ((d & 2047) << 17);
            atomicAdd(&hist[b], 1);
        }
    }
    __syncthreads();
    if (t < NBUCK) { basep[t] = atomicAdd(&bcnt[t], hist[t]); offp[t] = 0; }
    __syncthreads();
#pragma unroll
    for (int j = 0; j < 2; ++j) {
        if (bk[j] >= 0) {
            const int p   = atomicAdd(&offp[bk[j]], 1);
            const int pos = basep[bk[j]] + p;
            if (pos < BCAP) interm[bk[j] * BCAP + pos] = pk[j];
        }
    }
}

// ---------------------------------------------------------------------------
// k_binB R22: 1024 threads (was 256 — grid is only 49 blocks, so per-block
// wave count is the ONLY parallelism lever; 16 waves hide the stream latency
// 4x better). One wg per bucket: first-wave base reduce -> LDS degree count
// (2048 cursors) -> in-LDS prefix -> dense rowstart -> LDS-cursor scatter.
// ---------------------------------------------------------------------------
__global__ __launch_bounds__(1024) void k_binB(const int* __restrict__ interm,
                                               const int* __restrict__ bcnt,
                                               int* __restrict__ rowstart,
                                               int* __restrict__ csr)
{
    __shared__ int cnt[2048];
    __shared__ int wsum[1024];
    __shared__ int sbase;
    const int t      = threadIdx.x;
    const int bucket = blockIdx.x;

    if (t < 64) {                       // exclusive prefix for OUR bucket
        int v = (t < NBUCK && t < bucket) ? min(bcnt[t], BCAP) : 0;
#pragma unroll
        for (int off = 32; off >= 1; off >>= 1) v += __shfl_xor(v, off);
        if (t == 0) sbase = v;
    }
    if (bucket == 0 && t == 0) rowstart[N] = E;
    for (int i = t; i < 2048; i += 1024) cnt[i] = 0;
    __syncthreads();

    const int total = min(bcnt[bucket], BCAP);
    const int beg   = bucket * BCAP;
    for (int i = beg + t; i < beg + total; i += 1024)
        atomicAdd(&cnt[interm[i] >> 17], 1);
    __syncthreads();

    const int l0 = cnt[t * 2], l1 = cnt[t * 2 + 1];
    const int s  = l0 + l1;
    wsum[t] = s;
    __syncthreads();
    for (int off = 1; off < 1024; off <<= 1) {
        const int v = (t >= off) ? wsum[t - off] : 0;
        __syncthreads();
        wsum[t] += v;
        __syncthreads();
    }
    int run = sbase + wsum[t] - s;
    {
        const int node = bucket * 2048 + t * 2;
        cnt[t * 2] = run;
        if (node < N) rowstart[node] = run;
        run += l0;
        cnt[t * 2 + 1] = run;
        if (node + 1 < N) rowstart[node + 1] = run;
    }
    __syncthreads();

    for (int i = beg + t; i < beg + total; i += 1024) {
        const int p   = interm[i];
        const int pos = atomicAdd(&cnt[p >> 17], 1);
        csr[pos] = p & 0x1FFFF;
    }
}

// ---------------------------------------------------------------------------
// K_agg (R21, unchanged): one wave per dst node; lane = slot(4) x cg(16),
// 8 cols/lane; fp16 hW gather (v_fma_mix, f32 accum); 2-stage slot reduce.
// ---------------------------------------------------------------------------
__global__ __launch_bounds__(256) void k_agg(
    const int* __restrict__ rowstart, const int* __restrict__ csr,
    const float* __restrict__ aS, const float* __restrict__ aD,
    const __half* __restrict__ hWh, const float4* __restrict__ bgat4,
    __half* __restrict__ gout)
{
    const int t = threadIdx.x;
    const int w = t >> 6;
    const int n = blockIdx.x * 4 + w;
    const int lane = t & 63;
    const int slot = lane >> 4;      // 4 parallel edge slots
    const int cg   = lane & 15;      // colgroup: cols [cg*8, cg*8+8)
    const int head = cg >> 2;

    const int r0 = rowstart[n], r1 = rowstart[n + 1];
    const float adh = aD[n * 4 + head];

    float4 a0 = {0.f,0.f,0.f,0.f}, a1 = {0.f,0.f,0.f,0.f};
    float ss = 0.0f;

    if (slot == 0) {
        const float x0 = __expf(lrelu(aS[n * 4 + head] + adh));
        const float4 q = *(const float4*)&hWh[(size_t)n * HID + cg * 8];
        acc8h(q, x0, a0, a1);
        ss += x0;
    }

    int j = r0 + slot;
    for (; j + 4 < r1; j += 8) {
        const int s0 = csr[j], s1 = csr[j + 4];
        const float x0 = __expf(lrelu(aS[s0 * 4 + head] + adh));
        const float x1 = __expf(lrelu(aS[s1 * 4 + head] + adh));
        const float4 q0 = *(const float4*)&hWh[(size_t)s0 * HID + cg * 8];
        const float4 q1 = *(const float4*)&hWh[(size_t)s1 * HID + cg * 8];
        acc8h(q0, x0, a0, a1);
        acc8h(q1, x1, a0, a1);
        ss += x0 + x1;
    }
    if (j < r1) {
        const int s0 = csr[j];
        const float x0 = __expf(lrelu(aS[s0 * 4 + head] + adh));
        const float4 q = *(const float4*)&hWh[(size_t)s0 * HID + cg * 8];
        acc8h(q, x0, a0, a1);
        ss += x0;
    }

#pragma unroll
    for (int off = 16; off <= 32; off <<= 1) {
        a0.x += __shfl_xor(a0.x, off); a0.y += __shfl_xor(a0.y, off);
        a0.z += __shfl_xor(a0.z, off); a0.w += __shfl_xor(a0.w, off);
        a1.x += __shfl_xor(a1.x, off); a1.y += __shfl_xor(a1.y, off);
        a1.z += __shfl_xor(a1.z, off); a1.w += __shfl_xor(a1.w, off);
        ss += __shfl_xor(ss, off);
    }

    if (slot == 0) {
        const float inv = 1.0f / (ss + 1e-16f);
        const float4 bg0 = bgat4[cg * 2 + 0];
        const float4 bg1 = bgat4[cg * 2 + 1];
        const __half2 h0 = __float22half2_rn(make_float2(a0.x*inv+bg0.x, a0.y*inv+bg0.y));
        const __half2 h1 = __float22half2_rn(make_float2(a0.z*inv+bg0.z, a0.w*inv+bg0.w));
        const __half2 h2 = __float22half2_rn(make_float2(a1.x*inv+bg1.x, a1.y*inv+bg1.y));
        const __half2 h3 = __float22half2_rn(make_float2(a1.z*inv+bg1.z, a1.w*inv+bg1.w));
        uint4 p;
        p.x = *(const unsigned*)&h0; p.y = *(const unsigned*)&h1;
        p.z = *(const unsigned*)&h2; p.w = *(const unsigned*)&h3;
        *(uint4*)&gout[(size_t)n * HID + cg * 8] = p;
    }
}

// ---------------------------------------------------------------------------
// k_mlp (R16, unchanged): MFMA MLP head.
// ---------------------------------------------------------------------------
__global__ __launch_bounds__(256) void k_mlp(
    const __half* __restrict__ gout, const __half* __restrict__ Wpk3,
    const float* __restrict__ b1, const float* __restrict__ W2,
    const float* __restrict__ b2, float2* __restrict__ out)
{
    const int t = threadIdx.x;
    const int w = t >> 6, lane = t & 63;
    const int l15 = lane & 15, g = lane >> 4;
    const int rowbase = blockIdx.x * 64 + w * 16;
    const int arow = rowbase + l15;
    const bool arok = (arow < N);

    f32x4 acc[4];
#pragma unroll
    for (int tt = 0; tt < 4; ++tt)
#pragma unroll
        for (int q = 0; q < 4; ++q) acc[tt][q] = 0.0f;

#pragma unroll
    for (int ks = 0; ks < 4; ++ks) {
        half8 a;
#pragma unroll
        for (int i = 0; i < 8; ++i) a[i] = (_Float16)0;
        if (arok) a = *(const half8*)&gout[(size_t)arow * HID + ks * 32 + g * 8];
        const half8* bp = (const half8*)&Wpk3[ks * 2048 + lane * 8];
#pragma unroll
        for (int tt = 0; tt < 4; ++tt)
            acc[tt] = __builtin_amdgcn_mfma_f32_16x16x32_f16(a, bp[tt * 64], acc[tt], 0, 0, 0);
    }

    float l0[4] = {0.f, 0.f, 0.f, 0.f}, l1[4] = {0.f, 0.f, 0.f, 0.f};
#pragma unroll
    for (int tt = 0; tt < 4; ++tt) {
        const int col = tt * 16 + l15;
        const float bv = b1[col];
        const float2 wv = *(const float2*)&W2[col * 2];
#pragma unroll
        for (int rg = 0; rg < 4; ++rg) {
            const float h2 = fmaxf(acc[tt][rg] + bv, 0.0f);
            l0[rg] = fmaf(h2, wv.x, l0[rg]);
            l1[rg] = fmaf(h2, wv.y, l1[rg]);
        }
    }
#pragma unroll
    for (int off = 1; off <= 8; off <<= 1) {
#pragma unroll
        for (int rg = 0; rg < 4; ++rg) {
            l0[rg] += __shfl_xor(l0[rg], off);
            l1[rg] += __shfl_xor(l1[rg], off);
        }
    }
    if (l15 == 0) {
        const float b20 = b2[0], b21 = b2[1];
#pragma unroll
        for (int rg = 0; rg < 4; ++rg) {
            const int row = rowbase + g * 4 + rg;
            if (row < N) out[row] = make_float2(l0[rg] + b20, l1[rg] + b21);
        }
    }
}

extern "C" void kernel_launch(void* const* d_in, const int* in_sizes, int n_in,
                              void* d_out, int out_size, void* d_ws, size_t ws_size,
                              hipStream_t stream) {
    const float* x     = (const float*)d_in[0];
    const int*   ei    = (const int*)d_in[1];
    const float* Win   = (const float*)d_in[2];
    const float* bin   = (const float*)d_in[3];
    const float* Wgat  = (const float*)d_in[4];
    const float* attS  = (const float*)d_in[5];
    const float* attD  = (const float*)d_in[6];
    const float* bgat  = (const float*)d_in[7];
    const float* W1    = (const float*)d_in[8];
    const float* b1    = (const float*)d_in[9];
    const float* W2    = (const float*)d_in[10];
    const float* b2    = (const float*)d_in[11];

    char* ws = (char*)d_ws;
    __half* hWh   = (__half*)(ws + HW_OFF);
    __half* gout  = (__half*)(ws + GOUT_OFF);
    int*   interm = (int*)(ws + GOUT_OFF);    // aliases gout; dead before k_agg
    float* aS     = (float*)(ws + ASRC_OFF);
    float* aD     = (float*)(ws + ADST_OFF);
    int*   row    = (int*)(ws + ROW_OFF);
    int*   bcnt   = (int*)(ws + BCNT_OFF);
    __half* Wpk1  = (__half*)(ws + WPK1_OFF);
    __half* Wpk2  = (__half*)(ws + WPK2_OFF);
    __half* Wpk3  = (__half*)(ws + WPK3_OFF);
    int*   csr    = (int*)(ws + CSR_OFF);

    k_prep<<<192, 256, 0, stream>>>(Win, Wgat, W1, Wpk1, Wpk2, Wpk3, bcnt);
    k_proj<<<PROJ_NB, 512, 0, stream>>>(x, Wpk1, Wpk2, bin, attS, attD,
                                        hWh, aS, aD, ei, bcnt, interm);
    k_binB<<<NBUCK, 1024, 0, stream>>>(interm, bcnt, row, csr);
    k_agg<<<N / 4, 256, 0, stream>>>(row, csr, aS, aD, hWh,
                                     (const float4*)bgat, gout);
    k_mlp<<<MLP_NB, 256, 0, stream>>>(gout, Wpk3, b1, W2, b2, (float2*)d_out);
}